// Round 2
// baseline (899.182 us; speedup 1.0000x reference)
//
#include <hip/hip_runtime.h>
#include <cmath>

#define DIM 192
#define V (DIM * DIM * DIM)          // 7,077,888
#define V4 (V / 4)                   // 1,769,472 float4s
#define ROW4 (DIM / 4)               // 48 float4 per row
#define SLAB4 (ROW4 * DIM)           // 9216 float4 per z-slice

struct ZW { float w10[13], w15[13], w20[13], w30[13]; };
struct W2 { float wA[13], wB[13]; };

__device__ inline void fma4(float4& a, float w, const float4& v) {
    a.x += w * v.x; a.y += w * v.y; a.z += w * v.z; a.w += w * v.w;
}

// block-wide (256 thr) reduce of (s, s2) -> atomicAdd to two doubles
__device__ inline void block_reduce_atomic2(float s, float s2,
                                            double* d0, double* d1) {
    __shared__ float ws[4], ws2[4];
    __syncthreads();                       // protect reuse across calls
    for (int m = 1; m < 64; m <<= 1) {
        s  += __shfl_xor(s,  m, 64);
        s2 += __shfl_xor(s2, m, 64);
    }
    int wid = threadIdx.x >> 6, lane = threadIdx.x & 63;
    if (lane == 0) { ws[wid] = s; ws2[wid] = s2; }
    __syncthreads();
    if (threadIdx.x == 0) {
        atomicAdd(d0, (double)(ws[0] + ws[1] + ws[2] + ws[3]));
        atomicAdd(d1, (double)(ws2[0] + ws2[1] + ws2[2] + ws2[3]));
    }
}

// ---- fused z-pass for all 4 sigmas + ch0 (raw) statistics ------------------
__global__ __launch_bounds__(256) void zpass4(const float4* __restrict__ raw,
        float4* __restrict__ g10z, float4* __restrict__ g15z,
        float4* __restrict__ g20z, float4* __restrict__ g30z,
        ZW zw, double* __restrict__ sums) {
    int i = blockIdx.x * 256 + threadIdx.x;        // float4 index
    int z = i / SLAB4;
    float4 a10 = {0,0,0,0}, a15 = {0,0,0,0}, a20 = {0,0,0,0}, a30 = {0,0,0,0};
    float4 c = {0,0,0,0};
#pragma unroll
    for (int t = 0; t < 13; ++t) {
        int zz = z + t - 6;
        if (zz >= 0 && zz < DIM) {
            float4 v = raw[i + (t - 6) * SLAB4];
            fma4(a10, zw.w10[t], v);
            fma4(a15, zw.w15[t], v);
            fma4(a20, zw.w20[t], v);
            fma4(a30, zw.w30[t], v);
            if (t == 6) c = v;
        }
    }
    g10z[i] = a10; g15z[i] = a15; g20z[i] = a20; g30z[i] = a30;
    float s  = c.x + c.y + c.z + c.w;
    float s2 = c.x*c.x + c.y*c.y + c.z*c.z + c.w*c.w;
    block_reduce_atomic2(s, s2, &sums[0], &sums[1]);
}

// ---- fused y-pass for a sigma pair ----------------------------------------
template <int KS>
__global__ __launch_bounds__(256) void ypass2(const float4* __restrict__ inA,
        const float4* __restrict__ inB, float4* __restrict__ outA,
        float4* __restrict__ outB, W2 w) {
    int i = blockIdx.x * 256 + threadIdx.x;
    int y = (i / ROW4) % DIM;
    constexpr int H = KS / 2;
    float4 a = {0,0,0,0}, b = {0,0,0,0};
#pragma unroll
    for (int t = 0; t < KS; ++t) {
        int yy = y + t - H;
        if (yy >= 0 && yy < DIM) {
            int off = (t - H) * ROW4;
            fma4(a, w.wA[t], inA[i + off]);
            fma4(b, w.wB[t], inB[i + off]);
        }
    }
    outA[i] = a; outB[i] = b;
}

// ---- x-pass for a sigma pair, row-staged in LDS (in-place safe) -----------
// WRITE_G: p := conv(p,wA) [kept Gaussian], q := convA - convB (+stats)
// else:    p := convA - convB (+stats), q untouched
template <int KA, int KB, bool WRITE_G>
__global__ __launch_bounds__(256) void xpass2(float* __restrict__ p,
        float* __restrict__ q, W2 w, double* __restrict__ s0,
        double* __restrict__ s1) {
    constexpr int NROW = 8, NEL = NROW * DIM;      // 1536
    __shared__ float rp[NEL], rq[NEL];
    int base = blockIdx.x * NEL;
    for (int k = threadIdx.x; k < NEL; k += 256) {
        rp[k] = p[base + k];
        rq[k] = q[base + k];
    }
    __syncthreads();
    float s = 0.f, s2 = 0.f;
    for (int k = threadIdx.x; k < NEL; k += 256) {
        int x = k % DIM, r = k - x;
        float ca = 0.f, cb = 0.f;
#pragma unroll
        for (int t = 0; t < KA; ++t) {
            int xx = x + t - KA / 2;
            if (xx >= 0 && xx < DIM) ca += w.wA[t] * rp[r + xx];
        }
#pragma unroll
        for (int t = 0; t < KB; ++t) {
            int xx = x + t - KB / 2;
            if (xx >= 0 && xx < DIM) cb += w.wB[t] * rq[r + xx];
        }
        float ch = ca - cb;
        if constexpr (WRITE_G) {
            p[base + k] = ca;          // keep Gaussian (G sigma=1.0)
            q[base + k] = ch;          // ch1
        } else {
            p[base + k] = ch;          // ch2
        }
        s += ch; s2 += ch * ch;
    }
    block_reduce_atomic2(s, s2, s0, s1);
}

// ---- derivatives of G(1.0): ch3, ch4, ch5 + their statistics --------------
__global__ __launch_bounds__(256) void deriv4(const float4* __restrict__ g4,
        const float* __restrict__ g, float4* __restrict__ c3,
        float4* __restrict__ c4o, float4* __restrict__ c5,
        double* __restrict__ sums) {
    int i = blockIdx.x * 256 + threadIdx.x;
    int x4 = i % ROW4;
    int y = (i / ROW4) % DIM;
    int z = i / SLAB4;
    const float4 zero = {0,0,0,0};
    float4 c  = g4[i];
    float4 zm = (z > 0)       ? g4[i - SLAB4] : zero;
    float4 zp = (z < DIM - 1) ? g4[i + SLAB4] : zero;
    float4 ym = (y > 0)       ? g4[i - ROW4]  : zero;
    float4 yp = (y < DIM - 1) ? g4[i + ROW4]  : zero;
    float lf = (x4 > 0)        ? g[4 * i - 1] : 0.f;
    float rt = (x4 < ROW4 - 1) ? g[4 * i + 4] : 0.f;
    float xm[4] = { lf, c.x, c.y, c.z };
    float xp[4] = { c.y, c.z, c.w, rt };
    float cc[4] = { c.x, c.y, c.z, c.w };
    float zmv[4] = { zm.x, zm.y, zm.z, zm.w };
    float zpv[4] = { zp.x, zp.y, zp.z, zp.w };
    float ymv[4] = { ym.x, ym.y, ym.z, ym.w };
    float ypv[4] = { yp.x, yp.y, yp.z, yp.w };
    float o3[4], o4[4], o5[4];
    float s3 = 0, q3 = 0, s4 = 0, q4 = 0, s5 = 0, q5 = 0;
#pragma unroll
    for (int j = 0; j < 4; ++j) {
        float gx = 0.5f * (xp[j] - xm[j]);
        float gy = 0.5f * (ypv[j] - ymv[j]);
        float gz = 0.5f * (zpv[j] - zmv[j]);
        float lap = (xm[j] + xp[j] + ymv[j] + ypv[j] + zmv[j] + zpv[j] - 6.f * cc[j]);
        float gm = sqrtf(gx * gx + gy * gy + gz * gz + 1e-8f);
        float rr = fabsf(gy) / (fabsf(gx) + 1e-3f);
        float rb = fminf(rr, 20.f);
        o3[j] = lap; o4[j] = gm; o5[j] = rb;
        s3 += lap; q3 += lap * lap;
        s4 += gm;  q4 += gm * gm;
        s5 += rb;  q5 += rb * rb;
    }
    c3[i]  = make_float4(o3[0], o3[1], o3[2], o3[3]);
    c4o[i] = make_float4(o4[0], o4[1], o4[2], o4[3]);
    c5[i]  = make_float4(o5[0], o5[1], o5[2], o5[3]);
    block_reduce_atomic2(s3, q3, &sums[6],  &sums[7]);
    block_reduce_atomic2(s4, q4, &sums[8],  &sums[9]);
    block_reduce_atomic2(s5, q5, &sums[10], &sums[11]);
}

// ---- normalize (fuses raw -> ch0 copy) ------------------------------------
__global__ __launch_bounds__(256) void norm6(const float4* __restrict__ raw,
        float4* __restrict__ out, const double* __restrict__ sums) {
    int i = blockIdx.x * 256 + threadIdx.x;        // < 6*V4
    int c = i / V4;
    double s = sums[2 * c], s2 = sums[2 * c + 1];
    double mean = s / (double)V;
    double var  = (s2 - s * s / (double)V) / (double)(V - 1);
    float inv = (float)(1.0 / (sqrt(var) + 1e-8));
    float m = (float)mean;
    float4 v = (c == 0) ? raw[i] : out[i];
    v.x = (v.x - m) * inv;
    v.y = (v.y - m) * inv;
    v.z = (v.z - m) * inv;
    v.w = (v.w - m) * inv;
    out[i] = v;
}

// ---- host: Gaussian weights ------------------------------------------------
static void gauss_w(double sigma, float* w13, int center) {
    int ks = (int)(4.0 * sigma + 1.0);
    if (ks % 2 == 0) ks++;
    double tmp[13], sum = 0.0;
    for (int i = 0; i < ks; ++i) {
        double x = (double)(i - ks / 2);
        tmp[i] = exp(-0.5 * x * x / (sigma * sigma));
        sum += tmp[i];
    }
    for (int i = 0; i < 13; ++i) w13[i] = 0.f;
    int h = ks / 2;
    for (int i = 0; i < ks; ++i) w13[center + (i - h)] = (float)(tmp[i] / sum);
}

extern "C" void kernel_launch(void* const* d_in, const int* in_sizes, int n_in,
                              void* d_out, int out_size, void* d_ws, size_t ws_size,
                              hipStream_t stream) {
    const float* raw = (const float*)d_in[0];
    float* out = (float*)d_out;
    float* o[6];
    for (int c = 0; c < 6; ++c) o[c] = out + (size_t)c * V;
    double* sums = (double*)d_ws;

    hipMemsetAsync(d_ws, 0, 12 * sizeof(double), stream);

    // weights
    ZW zw;
    gauss_w(1.0, zw.w10, 6); gauss_w(1.5, zw.w15, 6);
    gauss_w(2.0, zw.w20, 6); gauss_w(3.0, zw.w30, 6);
    W2 ya;  gauss_w(1.0, ya.wA, 3);  gauss_w(1.5, ya.wB, 3);   // KS=7
    W2 yb;  gauss_w(2.0, yb.wA, 6);  gauss_w(3.0, yb.wB, 6);   // KS=13
    W2 xa;  gauss_w(1.0, xa.wA, 2);  gauss_w(1.5, xa.wB, 3);   // KA=5, KB=7
    W2 xb;  gauss_w(2.0, xb.wA, 4);  gauss_w(3.0, xb.wB, 6);   // KA=9, KB=13

    const float4* raw4 = (const float4*)raw;
    dim3 blk(256);
    int g4blocks = V4 / 256;                 // 6912

    // z-pass (all sigmas) + ch0 stats:  raw -> o2,o3,o4,o5
    zpass4<<<g4blocks, blk, 0, stream>>>(raw4, (float4*)o[2], (float4*)o[3],
                                         (float4*)o[4], (float4*)o[5], zw, sums);
    // y-pass sigma 1.0/1.5: o2,o3 -> o0,o1
    ypass2<7><<<g4blocks, blk, 0, stream>>>((const float4*)o[2], (const float4*)o[3],
                                            (float4*)o[0], (float4*)o[1], ya);
    // x-pass sigma 1.0/1.5 (in-place): o0 -> G10, o1 -> ch1 ; ch1 stats
    xpass2<5, 7, true><<<V / (8 * DIM), blk, 0, stream>>>(o[0], o[1], xa,
                                                          &sums[2], &sums[3]);
    // y-pass sigma 2.0/3.0: o4,o5 -> o2,o3
    ypass2<13><<<g4blocks, blk, 0, stream>>>((const float4*)o[4], (const float4*)o[5],
                                             (float4*)o[2], (float4*)o[3], yb);
    // x-pass sigma 2.0/3.0 (in-place): o2 -> ch2 ; ch2 stats
    xpass2<9, 13, false><<<V / (8 * DIM), blk, 0, stream>>>(o[2], o[3], xb,
                                                            &sums[4], &sums[5]);
    // derivatives of G10 (o0): ch3->o3, ch4->o4, ch5->o5 + stats
    deriv4<<<g4blocks, blk, 0, stream>>>((const float4*)o[0], o[0], (float4*)o[3],
                                         (float4*)o[4], (float4*)o[5], sums);
    // normalize all 6 channels (ch0 sourced from raw)
    norm6<<<(6 * V4) / 256, blk, 0, stream>>>(raw4, (float4*)out, sums);
}

// Round 3
// 266.366 us; speedup vs baseline: 3.3757x; 3.3757x over previous
//
#include <hip/hip_runtime.h>
#include <cmath>

#define DIM 192
#define V (DIM * DIM * DIM)          // 7,077,888
#define V4 (V / 4)                   // 1,769,472 float4s
#define ROW4 (DIM / 4)               // 48 float4 per row
#define SLAB4 (ROW4 * DIM)           // 9216 float4 per z-slice
#define NSLOT 64                     // hashed atomic slots per statistic

struct ZW { float w10[13], w15[13], w20[13], w30[13]; };
struct W2 { float wA[13], wB[13]; };

__device__ inline void fma4(float4& a, float w, const float4& v) {
    a.x += w * v.x; a.y += w * v.y; a.z += w * v.z; a.w += w * v.w;
}

// block-wide (256 thr) reduce of (s, s2) -> hashed-slot atomicAdd
// slots0/slots1 point at 64-double arrays for this statistic pair.
__device__ inline void block_reduce_slot2(float s, float s2,
                                          double* slots0, double* slots1) {
    __shared__ float ws[4], ws2[4];
    __syncthreads();                       // protect reuse across calls
    for (int m = 1; m < 64; m <<= 1) {
        s  += __shfl_xor(s,  m, 64);
        s2 += __shfl_xor(s2, m, 64);
    }
    int wid = threadIdx.x >> 6, lane = threadIdx.x & 63;
    if (lane == 0) { ws[wid] = s; ws2[wid] = s2; }
    __syncthreads();
    if (threadIdx.x == 0) {
        int slot = blockIdx.x & (NSLOT - 1);
        atomicAdd(&slots0[slot], (double)(ws[0] + ws[1] + ws[2] + ws[3]));
        atomicAdd(&slots1[slot], (double)(ws2[0] + ws2[1] + ws2[2] + ws2[3]));
    }
}

// ---- fused z-pass for all 4 sigmas + ch0 (raw) statistics ------------------
__global__ __launch_bounds__(256) void zpass4(const float4* __restrict__ raw,
        float4* __restrict__ g10z, float4* __restrict__ g15z,
        float4* __restrict__ g20z, float4* __restrict__ g30z,
        ZW zw, double* __restrict__ slots) {
    int i = blockIdx.x * 256 + threadIdx.x;        // float4 index
    int z = i / SLAB4;
    float4 a10 = {0,0,0,0}, a15 = {0,0,0,0}, a20 = {0,0,0,0}, a30 = {0,0,0,0};
    float4 c = {0,0,0,0};
#pragma unroll
    for (int t = 0; t < 13; ++t) {
        int zz = z + t - 6;
        if (zz >= 0 && zz < DIM) {
            float4 v = raw[i + (t - 6) * SLAB4];
            fma4(a10, zw.w10[t], v);
            fma4(a15, zw.w15[t], v);
            fma4(a20, zw.w20[t], v);
            fma4(a30, zw.w30[t], v);
            if (t == 6) c = v;
        }
    }
    g10z[i] = a10; g15z[i] = a15; g20z[i] = a20; g30z[i] = a30;
    float s  = c.x + c.y + c.z + c.w;
    float s2 = c.x*c.x + c.y*c.y + c.z*c.z + c.w*c.w;
    block_reduce_slot2(s, s2, slots + 0 * NSLOT, slots + 1 * NSLOT);
}

// ---- fused y-pass for a sigma pair ----------------------------------------
template <int KS>
__global__ __launch_bounds__(256) void ypass2(const float4* __restrict__ inA,
        const float4* __restrict__ inB, float4* __restrict__ outA,
        float4* __restrict__ outB, W2 w) {
    int i = blockIdx.x * 256 + threadIdx.x;
    int y = (i / ROW4) % DIM;
    constexpr int H = KS / 2;
    float4 a = {0,0,0,0}, b = {0,0,0,0};
#pragma unroll
    for (int t = 0; t < KS; ++t) {
        int yy = y + t - H;
        if (yy >= 0 && yy < DIM) {
            int off = (t - H) * ROW4;
            fma4(a, w.wA[t], inA[i + off]);
            fma4(b, w.wB[t], inB[i + off]);
        }
    }
    outA[i] = a; outB[i] = b;
}

// ---- x-pass for a sigma pair, row-staged in LDS (in-place safe) -----------
template <int KA, int KB, bool WRITE_G>
__global__ __launch_bounds__(256) void xpass2(float* __restrict__ p,
        float* __restrict__ q, W2 w, double* __restrict__ slots0,
        double* __restrict__ slots1) {
    constexpr int NROW = 8, NEL = NROW * DIM;      // 1536
    __shared__ float rp[NEL], rq[NEL];
    int base = blockIdx.x * NEL;
    for (int k = threadIdx.x; k < NEL; k += 256) {
        rp[k] = p[base + k];
        rq[k] = q[base + k];
    }
    __syncthreads();
    float s = 0.f, s2 = 0.f;
    for (int k = threadIdx.x; k < NEL; k += 256) {
        int x = k % DIM, r = k - x;
        float ca = 0.f, cb = 0.f;
#pragma unroll
        for (int t = 0; t < KA; ++t) {
            int xx = x + t - KA / 2;
            if (xx >= 0 && xx < DIM) ca += w.wA[t] * rp[r + xx];
        }
#pragma unroll
        for (int t = 0; t < KB; ++t) {
            int xx = x + t - KB / 2;
            if (xx >= 0 && xx < DIM) cb += w.wB[t] * rq[r + xx];
        }
        float ch = ca - cb;
        if constexpr (WRITE_G) {
            p[base + k] = ca;          // keep Gaussian (G sigma=1.0)
            q[base + k] = ch;          // ch1
        } else {
            p[base + k] = ch;          // ch2
        }
        s += ch; s2 += ch * ch;
    }
    block_reduce_slot2(s, s2, slots0, slots1);
}

// ---- derivatives of G(1.0): ch3, ch4, ch5 + their statistics --------------
__global__ __launch_bounds__(256) void deriv4(const float4* __restrict__ g4,
        const float* __restrict__ g, float4* __restrict__ c3,
        float4* __restrict__ c4o, float4* __restrict__ c5,
        double* __restrict__ slots) {
    int i = blockIdx.x * 256 + threadIdx.x;
    int x4 = i % ROW4;
    int y = (i / ROW4) % DIM;
    int z = i / SLAB4;
    const float4 zero = {0,0,0,0};
    float4 c  = g4[i];
    float4 zm = (z > 0)       ? g4[i - SLAB4] : zero;
    float4 zp = (z < DIM - 1) ? g4[i + SLAB4] : zero;
    float4 ym = (y > 0)       ? g4[i - ROW4]  : zero;
    float4 yp = (y < DIM - 1) ? g4[i + ROW4]  : zero;
    float lf = (x4 > 0)        ? g[4 * i - 1] : 0.f;
    float rt = (x4 < ROW4 - 1) ? g[4 * i + 4] : 0.f;
    float xm[4] = { lf, c.x, c.y, c.z };
    float xp[4] = { c.y, c.z, c.w, rt };
    float cc[4] = { c.x, c.y, c.z, c.w };
    float zmv[4] = { zm.x, zm.y, zm.z, zm.w };
    float zpv[4] = { zp.x, zp.y, zp.z, zp.w };
    float ymv[4] = { ym.x, ym.y, ym.z, ym.w };
    float ypv[4] = { yp.x, yp.y, yp.z, yp.w };
    float o3[4], o4[4], o5[4];
    float s3 = 0, q3 = 0, s4 = 0, q4 = 0, s5 = 0, q5 = 0;
#pragma unroll
    for (int j = 0; j < 4; ++j) {
        float gx = 0.5f * (xp[j] - xm[j]);
        float gy = 0.5f * (ypv[j] - ymv[j]);
        float gz = 0.5f * (zpv[j] - zmv[j]);
        float lap = (xm[j] + xp[j] + ymv[j] + ypv[j] + zmv[j] + zpv[j] - 6.f * cc[j]);
        float gm = sqrtf(gx * gx + gy * gy + gz * gz + 1e-8f);
        float rr = fabsf(gy) / (fabsf(gx) + 1e-3f);
        float rb = fminf(rr, 20.f);
        o3[j] = lap; o4[j] = gm; o5[j] = rb;
        s3 += lap; q3 += lap * lap;
        s4 += gm;  q4 += gm * gm;
        s5 += rb;  q5 += rb * rb;
    }
    c3[i]  = make_float4(o3[0], o3[1], o3[2], o3[3]);
    c4o[i] = make_float4(o4[0], o4[1], o4[2], o4[3]);
    c5[i]  = make_float4(o5[0], o5[1], o5[2], o5[3]);
    block_reduce_slot2(s3, q3, slots + 6 * NSLOT,  slots + 7 * NSLOT);
    block_reduce_slot2(s4, q4, slots + 8 * NSLOT,  slots + 9 * NSLOT);
    block_reduce_slot2(s5, q5, slots + 10 * NSLOT, slots + 11 * NSLOT);
}

// ---- fold 64 slots per statistic -> finals[12] ------------------------------
__global__ void finalize_sums(const double* __restrict__ slots,
                              double* __restrict__ finals) {
    int t = threadIdx.x;             // one block of 64
    if (t < 12) {
        double s = 0.0;
        for (int k = 0; k < NSLOT; ++k) s += slots[t * NSLOT + k];
        finals[t] = s;
    }
}

// ---- normalize (fuses raw -> ch0 copy) ------------------------------------
__global__ __launch_bounds__(256) void norm6(const float4* __restrict__ raw,
        float4* __restrict__ out, const double* __restrict__ finals) {
    int i = blockIdx.x * 256 + threadIdx.x;        // < 6*V4
    int c = i / V4;
    double s = finals[2 * c], s2 = finals[2 * c + 1];
    double mean = s / (double)V;
    double var  = (s2 - s * s / (double)V) / (double)(V - 1);
    float inv = (float)(1.0 / (sqrt(var) + 1e-8));
    float m = (float)mean;
    float4 v = (c == 0) ? raw[i] : out[i];
    v.x = (v.x - m) * inv;
    v.y = (v.y - m) * inv;
    v.z = (v.z - m) * inv;
    v.w = (v.w - m) * inv;
    out[i] = v;
}

// ---- host: Gaussian weights ------------------------------------------------
static void gauss_w(double sigma, float* w13, int center) {
    int ks = (int)(4.0 * sigma + 1.0);
    if (ks % 2 == 0) ks++;
    double tmp[13], sum = 0.0;
    for (int i = 0; i < ks; ++i) {
        double x = (double)(i - ks / 2);
        tmp[i] = exp(-0.5 * x * x / (sigma * sigma));
        sum += tmp[i];
    }
    for (int i = 0; i < 13; ++i) w13[i] = 0.f;
    int h = ks / 2;
    for (int i = 0; i < ks; ++i) w13[center + (i - h)] = (float)(tmp[i] / sum);
}

extern "C" void kernel_launch(void* const* d_in, const int* in_sizes, int n_in,
                              void* d_out, int out_size, void* d_ws, size_t ws_size,
                              hipStream_t stream) {
    const float* raw = (const float*)d_in[0];
    float* out = (float*)d_out;
    float* o[6];
    for (int c = 0; c < 6; ++c) o[c] = out + (size_t)c * V;
    double* slots  = (double*)d_ws;                 // 12 * 64 doubles
    double* finals = slots + 12 * NSLOT;            // 12 doubles

    hipMemsetAsync(d_ws, 0, (12 * NSLOT + 12) * sizeof(double), stream);

    // weights
    ZW zw;
    gauss_w(1.0, zw.w10, 6); gauss_w(1.5, zw.w15, 6);
    gauss_w(2.0, zw.w20, 6); gauss_w(3.0, zw.w30, 6);
    W2 ya;  gauss_w(1.0, ya.wA, 3);  gauss_w(1.5, ya.wB, 3);   // KS=7
    W2 yb;  gauss_w(2.0, yb.wA, 6);  gauss_w(3.0, yb.wB, 6);   // KS=13
    W2 xa;  gauss_w(1.0, xa.wA, 2);  gauss_w(1.5, xa.wB, 3);   // KA=5, KB=7
    W2 xb;  gauss_w(2.0, xb.wA, 4);  gauss_w(3.0, xb.wB, 6);   // KA=9, KB=13

    const float4* raw4 = (const float4*)raw;
    dim3 blk(256);
    int g4blocks = V4 / 256;                 // 6912

    // z-pass (all sigmas) + ch0 stats:  raw -> o2,o3,o4,o5
    zpass4<<<g4blocks, blk, 0, stream>>>(raw4, (float4*)o[2], (float4*)o[3],
                                         (float4*)o[4], (float4*)o[5], zw, slots);
    // y-pass sigma 1.0/1.5: o2,o3 -> o0,o1
    ypass2<7><<<g4blocks, blk, 0, stream>>>((const float4*)o[2], (const float4*)o[3],
                                            (float4*)o[0], (float4*)o[1], ya);
    // x-pass sigma 1.0/1.5 (in-place): o0 -> G10, o1 -> ch1 ; ch1 stats
    xpass2<5, 7, true><<<V / (8 * DIM), blk, 0, stream>>>(o[0], o[1], xa,
                                       slots + 2 * NSLOT, slots + 3 * NSLOT);
    // y-pass sigma 2.0/3.0: o4,o5 -> o2,o3
    ypass2<13><<<g4blocks, blk, 0, stream>>>((const float4*)o[4], (const float4*)o[5],
                                             (float4*)o[2], (float4*)o[3], yb);
    // x-pass sigma 2.0/3.0 (in-place): o2 -> ch2 ; ch2 stats
    xpass2<9, 13, false><<<V / (8 * DIM), blk, 0, stream>>>(o[2], o[3], xb,
                                       slots + 4 * NSLOT, slots + 5 * NSLOT);
    // derivatives of G10 (o0): ch3->o3, ch4->o4, ch5->o5 + stats
    deriv4<<<g4blocks, blk, 0, stream>>>((const float4*)o[0], o[0], (float4*)o[3],
                                         (float4*)o[4], (float4*)o[5], slots);
    // fold slots -> finals
    finalize_sums<<<1, 64, 0, stream>>>(slots, finals);
    // normalize all 6 channels (ch0 sourced from raw)
    norm6<<<(6 * V4) / 256, blk, 0, stream>>>(raw4, (float4*)out, finals);
}

// Round 4
// 251.825 us; speedup vs baseline: 3.5707x; 1.0577x over previous
//
#include <hip/hip_runtime.h>
#include <cmath>

#define DIM 192
#define V (DIM * DIM * DIM)          // 7,077,888
#define V4 (V / 4)                   // 1,769,472 float4s
#define ROW4 (DIM / 4)               // 48 float4 per row
#define SLAB4 (ROW4 * DIM)           // 9216 float4 per z-slice
#define NSLOT 64                     // hashed atomic slots per statistic

struct ZW { float w10[13], w15[13], w20[13], w30[13]; };
struct W2 { float wA[13], wB[13]; };

__device__ inline void fma4(float4& a, float w, const float4& v) {
    a.x += w * v.x; a.y += w * v.y; a.z += w * v.z; a.w += w * v.w;
}

// block-wide (256 thr) reduce of (s, s2) -> hashed-slot atomicAdd
__device__ inline void block_reduce_slot2(float s, float s2,
                                          double* slots0, double* slots1) {
    __shared__ float ws[4], ws2[4];
    __syncthreads();                       // protect reuse across calls
    for (int m = 1; m < 64; m <<= 1) {
        s  += __shfl_xor(s,  m, 64);
        s2 += __shfl_xor(s2, m, 64);
    }
    int wid = threadIdx.x >> 6, lane = threadIdx.x & 63;
    if (lane == 0) { ws[wid] = s; ws2[wid] = s2; }
    __syncthreads();
    if (threadIdx.x == 0) {
        int slot = blockIdx.x & (NSLOT - 1);
        atomicAdd(&slots0[slot], (double)(ws[0] + ws[1] + ws[2] + ws[3]));
        atomicAdd(&slots1[slot], (double)(ws2[0] + ws2[1] + ws2[2] + ws2[3]));
    }
}

// ---- fused z-pass for all 4 sigmas + ch0 (raw) statistics ------------------
__global__ __launch_bounds__(256) void zpass4(const float4* __restrict__ raw,
        float4* __restrict__ g10z, float4* __restrict__ g15z,
        float4* __restrict__ g20z, float4* __restrict__ g30z,
        ZW zw, double* __restrict__ slots) {
    int i = blockIdx.x * 256 + threadIdx.x;        // float4 index
    int z = i / SLAB4;
    float4 a10 = {0,0,0,0}, a15 = {0,0,0,0}, a20 = {0,0,0,0}, a30 = {0,0,0,0};
    float4 c = {0,0,0,0};
#pragma unroll
    for (int t = 0; t < 13; ++t) {
        int zz = z + t - 6;
        if (zz >= 0 && zz < DIM) {
            float4 v = raw[i + (t - 6) * SLAB4];
            fma4(a10, zw.w10[t], v);
            fma4(a15, zw.w15[t], v);
            fma4(a20, zw.w20[t], v);
            fma4(a30, zw.w30[t], v);
            if (t == 6) c = v;
        }
    }
    g10z[i] = a10; g15z[i] = a15; g20z[i] = a20; g30z[i] = a30;
    float s  = c.x + c.y + c.z + c.w;
    float s2 = c.x*c.x + c.y*c.y + c.z*c.z + c.w*c.w;
    block_reduce_slot2(s, s2, slots + 0 * NSLOT, slots + 1 * NSLOT);
}

// ---- fused y+x pass for a sigma pair ---------------------------------------
// y-conv reads global (L2-absorbed halo overlap), result staged in LDS,
// x-conv consumes LDS.  outC = convA - convB (+stats); outG = convA (G10).
template <int KYA, int KYB, int KXA, int KXB, bool WRITE_G>
__global__ __launch_bounds__(256) void yx2(
        const float4* __restrict__ inA, const float4* __restrict__ inB,
        float4* __restrict__ outG, float4* __restrict__ outC,
        W2 wy, W2 wx, double* __restrict__ s0, double* __restrict__ s1) {
    constexpr int TY = 16;
    constexpr int NF4 = TY * ROW4;            // 768 float4 per tile
    __shared__ float yA[TY * DIM], yB[TY * DIM];
    int tile = blockIdx.x;
    int z  = tile / (DIM / TY);
    int y0 = (tile % (DIM / TY)) * TY;
    const int slab = z * SLAB4;               // float4 index of slice start
    // y-convolution into LDS
    for (int e = threadIdx.x; e < NF4; e += 256) {
        int r  = e / ROW4;
        int x4 = e % ROW4;
        int y  = y0 + r;
        float4 a = {0,0,0,0}, b = {0,0,0,0};
#pragma unroll
        for (int t = 0; t < KYA; ++t) {
            int yy = y + t - KYA / 2;
            if (yy >= 0 && yy < DIM) fma4(a, wy.wA[t], inA[slab + yy * ROW4 + x4]);
        }
#pragma unroll
        for (int t = 0; t < KYB; ++t) {
            int yy = y + t - KYB / 2;
            if (yy >= 0 && yy < DIM) fma4(b, wy.wB[t], inB[slab + yy * ROW4 + x4]);
        }
        int o = r * DIM + x4 * 4;
        yA[o] = a.x; yA[o + 1] = a.y; yA[o + 2] = a.z; yA[o + 3] = a.w;
        yB[o] = b.x; yB[o + 1] = b.y; yB[o + 2] = b.z; yB[o + 3] = b.w;
    }
    __syncthreads();
    float s = 0.f, s2 = 0.f;
    for (int e = threadIdx.x; e < NF4; e += 256) {
        int r = e / ROW4, x4 = e % ROW4;
        int rb = r * DIM;
        float g[4], c[4];
#pragma unroll
        for (int j = 0; j < 4; ++j) {
            int x = x4 * 4 + j;
            float ca = 0.f, cb = 0.f;
#pragma unroll
            for (int t = 0; t < KXA; ++t) {
                int xx = x + t - KXA / 2;
                if (xx >= 0 && xx < DIM) ca += wx.wA[t] * yA[rb + xx];
            }
#pragma unroll
            for (int t = 0; t < KXB; ++t) {
                int xx = x + t - KXB / 2;
                if (xx >= 0 && xx < DIM) cb += wx.wB[t] * yB[rb + xx];
            }
            float ch = ca - cb;
            g[j] = ca; c[j] = ch;
            s += ch; s2 += ch * ch;
        }
        int gi = slab + (y0 + r) * ROW4 + x4;
        if constexpr (WRITE_G) outG[gi] = make_float4(g[0], g[1], g[2], g[3]);
        outC[gi] = make_float4(c[0], c[1], c[2], c[3]);
    }
    block_reduce_slot2(s, s2, s0, s1);
}

// ---- shared derivative math -------------------------------------------------
__device__ inline void deriv_point(const float4* g4, const float* g, int i,
                                   float o3[4], float o4[4], float o5[4]) {
    int x4 = i % ROW4;
    int y  = (i / ROW4) % DIM;
    int z  = i / SLAB4;
    const float4 zero = {0,0,0,0};
    float4 c  = g4[i];
    float4 zm = (z > 0)       ? g4[i - SLAB4] : zero;
    float4 zp = (z < DIM - 1) ? g4[i + SLAB4] : zero;
    float4 ym = (y > 0)       ? g4[i - ROW4]  : zero;
    float4 yp = (y < DIM - 1) ? g4[i + ROW4]  : zero;
    float lf = (x4 > 0)        ? g[4 * i - 1] : 0.f;
    float rt = (x4 < ROW4 - 1) ? g[4 * i + 4] : 0.f;
    float xm[4] = { lf, c.x, c.y, c.z };
    float xp[4] = { c.y, c.z, c.w, rt };
    float cc[4] = { c.x, c.y, c.z, c.w };
    float zmv[4] = { zm.x, zm.y, zm.z, zm.w };
    float zpv[4] = { zp.x, zp.y, zp.z, zp.w };
    float ymv[4] = { ym.x, ym.y, ym.z, ym.w };
    float ypv[4] = { yp.x, yp.y, yp.z, yp.w };
#pragma unroll
    for (int j = 0; j < 4; ++j) {
        float gx = 0.5f * (xp[j] - xm[j]);
        float gy = 0.5f * (ypv[j] - ymv[j]);
        float gz = 0.5f * (zpv[j] - zmv[j]);
        o3[j] = xm[j] + xp[j] + ymv[j] + ypv[j] + zmv[j] + zpv[j] - 6.f * cc[j];
        o4[j] = sqrtf(gx * gx + gy * gy + gz * gz + 1e-8f);
        o5[j] = fminf(fabsf(gy) / (fabsf(gx) + 1e-3f), 20.f);
    }
}

// ---- ch3/4/5 statistics only (no writes) -----------------------------------
__global__ __launch_bounds__(256) void deriv_stats(const float4* __restrict__ g4,
        const float* __restrict__ g, double* __restrict__ slots) {
    int i = blockIdx.x * 256 + threadIdx.x;
    float o3[4], o4[4], o5[4];
    deriv_point(g4, g, i, o3, o4, o5);
    float s3 = 0, q3 = 0, s4 = 0, q4 = 0, s5 = 0, q5 = 0;
#pragma unroll
    for (int j = 0; j < 4; ++j) {
        s3 += o3[j]; q3 += o3[j] * o3[j];
        s4 += o4[j]; q4 += o4[j] * o4[j];
        s5 += o5[j]; q5 += o5[j] * o5[j];
    }
    block_reduce_slot2(s3, q3, slots + 6 * NSLOT,  slots + 7 * NSLOT);
    block_reduce_slot2(s4, q4, slots + 8 * NSLOT,  slots + 9 * NSLOT);
    block_reduce_slot2(s5, q5, slots + 10 * NSLOT, slots + 11 * NSLOT);
}

// ---- fold 64 slots per statistic -> finals[12] ------------------------------
__global__ void finalize_sums(const double* __restrict__ slots,
                              double* __restrict__ finals) {
    int t = threadIdx.x;
    if (t < 12) {
        double s = 0.0;
        for (int k = 0; k < NSLOT; ++k) s += slots[t * NSLOT + k];
        finals[t] = s;
    }
}

__device__ inline void mean_inv(const double* finals, int c, float& m, float& inv) {
    double s = finals[2 * c], s2 = finals[2 * c + 1];
    double mean = s / (double)V;
    double var  = (s2 - s * s / (double)V) / (double)(V - 1);
    m   = (float)mean;
    inv = (float)(1.0 / (sqrt(var) + 1e-8));
}

// ---- recompute derivatives from G10 and write NORMALIZED ch3/4/5 -----------
__global__ __launch_bounds__(256) void norm_deriv(const float4* __restrict__ g4,
        const float* __restrict__ g, float4* __restrict__ c3,
        float4* __restrict__ c4o, float4* __restrict__ c5,
        const double* __restrict__ finals) {
    int i = blockIdx.x * 256 + threadIdx.x;
    float o3[4], o4[4], o5[4];
    deriv_point(g4, g, i, o3, o4, o5);
    float m3, i3, m4, i4, m5, i5;
    mean_inv(finals, 3, m3, i3);
    mean_inv(finals, 4, m4, i4);
    mean_inv(finals, 5, m5, i5);
    c3[i]  = make_float4((o3[0]-m3)*i3, (o3[1]-m3)*i3, (o3[2]-m3)*i3, (o3[3]-m3)*i3);
    c4o[i] = make_float4((o4[0]-m4)*i4, (o4[1]-m4)*i4, (o4[2]-m4)*i4, (o4[3]-m4)*i4);
    c5[i]  = make_float4((o5[0]-m5)*i5, (o5[1]-m5)*i5, (o5[2]-m5)*i5, (o5[3]-m5)*i5);
}

// ---- normalize ch0 (from raw), ch1, ch2 (in place) --------------------------
__global__ __launch_bounds__(256) void norm_abc(const float4* __restrict__ raw,
        float4* __restrict__ out, const double* __restrict__ finals) {
    int i = blockIdx.x * 256 + threadIdx.x;        // < 3*V4
    int c = i / V4;
    int ii = i - c * V4;
    float m, inv;
    mean_inv(finals, c, m, inv);
    float4 v = (c == 0) ? raw[ii] : out[(size_t)c * V4 + ii];
    v.x = (v.x - m) * inv;
    v.y = (v.y - m) * inv;
    v.z = (v.z - m) * inv;
    v.w = (v.w - m) * inv;
    out[(size_t)c * V4 + ii] = v;
}

// ---- host: Gaussian weights ------------------------------------------------
static void gauss_w(double sigma, float* w13, int center) {
    int ks = (int)(4.0 * sigma + 1.0);
    if (ks % 2 == 0) ks++;
    double tmp[13], sum = 0.0;
    for (int i = 0; i < ks; ++i) {
        double x = (double)(i - ks / 2);
        tmp[i] = exp(-0.5 * x * x / (sigma * sigma));
        sum += tmp[i];
    }
    for (int i = 0; i < 13; ++i) w13[i] = 0.f;
    int h = ks / 2;
    for (int i = 0; i < ks; ++i) w13[center + (i - h)] = (float)(tmp[i] / sum);
}

extern "C" void kernel_launch(void* const* d_in, const int* in_sizes, int n_in,
                              void* d_out, int out_size, void* d_ws, size_t ws_size,
                              hipStream_t stream) {
    const float* raw = (const float*)d_in[0];
    float* out = (float*)d_out;
    float* o[6];
    for (int c = 0; c < 6; ++c) o[c] = out + (size_t)c * V;
    double* slots  = (double*)d_ws;                 // 12 * 64 doubles
    double* finals = slots + 12 * NSLOT;            // 12 doubles

    hipMemsetAsync(d_ws, 0, (12 * NSLOT + 12) * sizeof(double), stream);

    // weights (each centered at its own KS/2)
    ZW zw;
    gauss_w(1.0, zw.w10, 6); gauss_w(1.5, zw.w15, 6);
    gauss_w(2.0, zw.w20, 6); gauss_w(3.0, zw.w30, 6);
    W2 wyA; gauss_w(1.0, wyA.wA, 2);  gauss_w(1.5, wyA.wB, 3);   // KY 5, 7
    W2 wxA; gauss_w(1.0, wxA.wA, 2);  gauss_w(1.5, wxA.wB, 3);   // KX 5, 7
    W2 wyB; gauss_w(2.0, wyB.wA, 4);  gauss_w(3.0, wyB.wB, 6);   // KY 9, 13
    W2 wxB; gauss_w(2.0, wxB.wA, 4);  gauss_w(3.0, wxB.wB, 6);   // KX 9, 13

    const float4* raw4 = (const float4*)raw;
    dim3 blk(256);
    int g4blocks = V4 / 256;                 // 6912
    int yxblocks = DIM * (DIM / 16);         // 2304

    // z-pass (all sigmas) + ch0 stats:  raw -> o2(g10z),o3(g15z),o4(g20z),o5(g30z)
    zpass4<<<g4blocks, blk, 0, stream>>>(raw4, (float4*)o[2], (float4*)o[3],
                                         (float4*)o[4], (float4*)o[5], zw, slots);
    // fused y+x, sigma 1.0/1.5: o2,o3 -> G10 (o0), ch1 (o1) + ch1 stats
    yx2<5, 7, 5, 7, true><<<yxblocks, blk, 0, stream>>>(
        (const float4*)o[2], (const float4*)o[3], (float4*)o[0], (float4*)o[1],
        wyA, wxA, slots + 2 * NSLOT, slots + 3 * NSLOT);
    // fused y+x, sigma 2.0/3.0: o4,o5 -> ch2 (o2) + ch2 stats
    yx2<9, 13, 9, 13, false><<<yxblocks, blk, 0, stream>>>(
        (const float4*)o[4], (const float4*)o[5], nullptr, (float4*)o[2],
        wyB, wxB, slots + 4 * NSLOT, slots + 5 * NSLOT);
    // ch3/4/5 statistics from G10 (o0), no writes
    deriv_stats<<<g4blocks, blk, 0, stream>>>((const float4*)o[0], o[0], slots);
    // fold slots -> finals
    finalize_sums<<<1, 64, 0, stream>>>(slots, finals);
    // recompute derivatives of G10 -> write normalized ch3(o3), ch4(o4), ch5(o5)
    norm_deriv<<<g4blocks, blk, 0, stream>>>((const float4*)o[0], o[0],
        (float4*)o[3], (float4*)o[4], (float4*)o[5], finals);
    // normalize ch0 (from raw) -> o0, ch1 -> o1, ch2 -> o2
    norm_abc<<<(3 * V4) / 256, blk, 0, stream>>>(raw4, (float4*)out, finals);
}

// Round 5
// 246.833 us; speedup vs baseline: 3.6429x; 1.0202x over previous
//
#include <hip/hip_runtime.h>
#include <hip/hip_fp16.h>
#include <cmath>

#define DIM 192
#define V (DIM * DIM * DIM)          // 7,077,888
#define V4 (V / 4)                   // 1,769,472 float4s
#define ROW4 (DIM / 4)               // 48 float4 per row
#define SLAB4 (ROW4 * DIM)           // 9216 float4 per z-slice
#define NSLOT 64                     // hashed atomic slots per statistic

struct ZW { float w10[13], w15[13], w20[13], w30[13]; };
struct W2 { float wA[13], wB[13]; };

__device__ inline void fma4(float4& a, float w, const float4& v) {
    a.x += w * v.x; a.y += w * v.y; a.z += w * v.z; a.w += w * v.w;
}

// ---- fp16 pack/unpack (4 values in a uint2) --------------------------------
__device__ inline uint2 pack_h4(float4 v) {
    __half2 lo = __floats2half2_rn(v.x, v.y);
    __half2 hi = __floats2half2_rn(v.z, v.w);
    uint2 r;
    r.x = *(unsigned int*)&lo;
    r.y = *(unsigned int*)&hi;
    return r;
}
__device__ inline float4 unpack_h4(uint2 p) {
    __half2 lo = *(__half2*)&p.x;
    __half2 hi = *(__half2*)&p.y;
    float2 a = __half22float2(lo), b = __half22float2(hi);
    return make_float4(a.x, a.y, b.x, b.y);
}
__device__ inline float4 ld4(const float4* p, int i) { return p[i]; }
__device__ inline float4 ld4(const uint2*  p, int i) { return unpack_h4(p[i]); }

// block-wide (256 thr) reduce of (s, s2) -> hashed-slot atomicAdd
__device__ inline void block_reduce_slot2(float s, float s2,
                                          double* slots0, double* slots1) {
    __shared__ float ws[4], ws2[4];
    __syncthreads();                       // protect reuse across calls
    for (int m = 1; m < 64; m <<= 1) {
        s  += __shfl_xor(s,  m, 64);
        s2 += __shfl_xor(s2, m, 64);
    }
    int wid = threadIdx.x >> 6, lane = threadIdx.x & 63;
    if (lane == 0) { ws[wid] = s; ws2[wid] = s2; }
    __syncthreads();
    if (threadIdx.x == 0) {
        int slot = blockIdx.x & (NSLOT - 1);
        atomicAdd(&slots0[slot], (double)(ws[0] + ws[1] + ws[2] + ws[3]));
        atomicAdd(&slots1[slot], (double)(ws2[0] + ws2[1] + ws2[2] + ws2[3]));
    }
}

// ---- fused z-pass for all 4 sigmas + ch0 (raw) statistics ------------------
// g10z fp32 (feeds ch3/4/5 path), g15z/g20z/g30z fp16 (feed ch1/ch2 only)
__global__ __launch_bounds__(256) void zpass4(const float4* __restrict__ raw,
        float4* __restrict__ g10z, uint2* __restrict__ g15z,
        uint2* __restrict__ g20z, uint2* __restrict__ g30z,
        ZW zw, double* __restrict__ slots) {
    int i = blockIdx.x * 256 + threadIdx.x;        // float4 index
    int z = i / SLAB4;
    float4 a10 = {0,0,0,0}, a15 = {0,0,0,0}, a20 = {0,0,0,0}, a30 = {0,0,0,0};
    float4 c = {0,0,0,0};
#pragma unroll
    for (int t = 0; t < 13; ++t) {
        int zz = z + t - 6;
        if (zz >= 0 && zz < DIM) {
            float4 v = raw[i + (t - 6) * SLAB4];
            fma4(a10, zw.w10[t], v);
            fma4(a15, zw.w15[t], v);
            fma4(a20, zw.w20[t], v);
            fma4(a30, zw.w30[t], v);
            if (t == 6) c = v;
        }
    }
    g10z[i] = a10;
    g15z[i] = pack_h4(a15);
    g20z[i] = pack_h4(a20);
    g30z[i] = pack_h4(a30);
    float s  = c.x + c.y + c.z + c.w;
    float s2 = c.x*c.x + c.y*c.y + c.z*c.z + c.w*c.w;
    block_reduce_slot2(s, s2, slots + 0 * NSLOT, slots + 1 * NSLOT);
}

// ---- fused y+x pass for a sigma pair ---------------------------------------
template <int KYA, int KYB, int KXA, int KXB, bool WRITE_G,
          typename TA, typename TB>
__global__ __launch_bounds__(256) void yx2(
        const TA* __restrict__ inA, const TB* __restrict__ inB,
        float4* __restrict__ outG, float4* __restrict__ outC,
        W2 wy, W2 wx, double* __restrict__ s0, double* __restrict__ s1) {
    constexpr int TY = 16;
    constexpr int NF4 = TY * ROW4;            // 768 float4 per tile
    __shared__ float yA[TY * DIM], yB[TY * DIM];
    int tile = blockIdx.x;
    int z  = tile / (DIM / TY);
    int y0 = (tile % (DIM / TY)) * TY;
    const int slab = z * SLAB4;               // float4 index of slice start
    // y-convolution into LDS
    for (int e = threadIdx.x; e < NF4; e += 256) {
        int r  = e / ROW4;
        int x4 = e % ROW4;
        int y  = y0 + r;
        float4 a = {0,0,0,0}, b = {0,0,0,0};
#pragma unroll
        for (int t = 0; t < KYA; ++t) {
            int yy = y + t - KYA / 2;
            if (yy >= 0 && yy < DIM) fma4(a, wy.wA[t], ld4(inA, slab + yy * ROW4 + x4));
        }
#pragma unroll
        for (int t = 0; t < KYB; ++t) {
            int yy = y + t - KYB / 2;
            if (yy >= 0 && yy < DIM) fma4(b, wy.wB[t], ld4(inB, slab + yy * ROW4 + x4));
        }
        int o = r * DIM + x4 * 4;
        yA[o] = a.x; yA[o + 1] = a.y; yA[o + 2] = a.z; yA[o + 3] = a.w;
        yB[o] = b.x; yB[o + 1] = b.y; yB[o + 2] = b.z; yB[o + 3] = b.w;
    }
    __syncthreads();
    float s = 0.f, s2 = 0.f;
    for (int e = threadIdx.x; e < NF4; e += 256) {
        int r = e / ROW4, x4 = e % ROW4;
        int rb = r * DIM;
        float g[4], c[4];
#pragma unroll
        for (int j = 0; j < 4; ++j) {
            int x = x4 * 4 + j;
            float ca = 0.f, cb = 0.f;
#pragma unroll
            for (int t = 0; t < KXA; ++t) {
                int xx = x + t - KXA / 2;
                if (xx >= 0 && xx < DIM) ca += wx.wA[t] * yA[rb + xx];
            }
#pragma unroll
            for (int t = 0; t < KXB; ++t) {
                int xx = x + t - KXB / 2;
                if (xx >= 0 && xx < DIM) cb += wx.wB[t] * yB[rb + xx];
            }
            float ch = ca - cb;
            g[j] = ca; c[j] = ch;
            s += ch; s2 += ch * ch;
        }
        int gi = slab + (y0 + r) * ROW4 + x4;
        if constexpr (WRITE_G) outG[gi] = make_float4(g[0], g[1], g[2], g[3]);
        outC[gi] = make_float4(c[0], c[1], c[2], c[3]);
    }
    block_reduce_slot2(s, s2, s0, s1);
}

// ---- shared derivative math -------------------------------------------------
__device__ inline void deriv_point(const float4* g4, const float* g, int i,
                                   float o3[4], float o4[4], float o5[4]) {
    int x4 = i % ROW4;
    int y  = (i / ROW4) % DIM;
    int z  = i / SLAB4;
    const float4 zero = {0,0,0,0};
    float4 c  = g4[i];
    float4 zm = (z > 0)       ? g4[i - SLAB4] : zero;
    float4 zp = (z < DIM - 1) ? g4[i + SLAB4] : zero;
    float4 ym = (y > 0)       ? g4[i - ROW4]  : zero;
    float4 yp = (y < DIM - 1) ? g4[i + ROW4]  : zero;
    float lf = (x4 > 0)        ? g[4 * i - 1] : 0.f;
    float rt = (x4 < ROW4 - 1) ? g[4 * i + 4] : 0.f;
    float xm[4] = { lf, c.x, c.y, c.z };
    float xp[4] = { c.y, c.z, c.w, rt };
    float cc[4] = { c.x, c.y, c.z, c.w };
    float zmv[4] = { zm.x, zm.y, zm.z, zm.w };
    float zpv[4] = { zp.x, zp.y, zp.z, zp.w };
    float ymv[4] = { ym.x, ym.y, ym.z, ym.w };
    float ypv[4] = { yp.x, yp.y, yp.z, yp.w };
#pragma unroll
    for (int j = 0; j < 4; ++j) {
        float gx = 0.5f * (xp[j] - xm[j]);
        float gy = 0.5f * (ypv[j] - ymv[j]);
        float gz = 0.5f * (zpv[j] - zmv[j]);
        o3[j] = xm[j] + xp[j] + ymv[j] + ypv[j] + zmv[j] + zpv[j] - 6.f * cc[j];
        o4[j] = sqrtf(gx * gx + gy * gy + gz * gz + 1e-8f);
        o5[j] = fminf(fabsf(gy) / (fabsf(gx) + 1e-3f), 20.f);
    }
}

// ---- ch3/4/5 statistics only (no writes) -----------------------------------
__global__ __launch_bounds__(256) void deriv_stats(const float4* __restrict__ g4,
        const float* __restrict__ g, double* __restrict__ slots) {
    int i = blockIdx.x * 256 + threadIdx.x;
    float o3[4], o4[4], o5[4];
    deriv_point(g4, g, i, o3, o4, o5);
    float s3 = 0, q3 = 0, s4 = 0, q4 = 0, s5 = 0, q5 = 0;
#pragma unroll
    for (int j = 0; j < 4; ++j) {
        s3 += o3[j]; q3 += o3[j] * o3[j];
        s4 += o4[j]; q4 += o4[j] * o4[j];
        s5 += o5[j]; q5 += o5[j] * o5[j];
    }
    block_reduce_slot2(s3, q3, slots + 6 * NSLOT,  slots + 7 * NSLOT);
    block_reduce_slot2(s4, q4, slots + 8 * NSLOT,  slots + 9 * NSLOT);
    block_reduce_slot2(s5, q5, slots + 10 * NSLOT, slots + 11 * NSLOT);
}

// ---- fold 64 slots per statistic -> finals[12] (warp-parallel) --------------
__global__ void finalize_sums(const double* __restrict__ slots,
                              double* __restrict__ finals) {
    int w = threadIdx.x >> 6, lane = threadIdx.x & 63;   // 256 thr = 4 waves
    for (int t = w; t < 12; t += 4) {
        double s = slots[t * NSLOT + lane];              // NSLOT == 64
        for (int m = 1; m < 64; m <<= 1) s += __shfl_xor(s, m, 64);
        if (lane == 0) finals[t] = s;
    }
}

__device__ inline void mean_inv(const double* finals, int c, float& m, float& inv) {
    double s = finals[2 * c], s2 = finals[2 * c + 1];
    double mean = s / (double)V;
    double var  = (s2 - s * s / (double)V) / (double)(V - 1);
    m   = (float)mean;
    inv = (float)(1.0 / (sqrt(var) + 1e-8));
}

// ---- recompute derivatives from G10 and write NORMALIZED ch3/4/5 -----------
__global__ __launch_bounds__(256) void norm_deriv(const float4* __restrict__ g4,
        const float* __restrict__ g, float4* __restrict__ c3,
        float4* __restrict__ c4o, float4* __restrict__ c5,
        const double* __restrict__ finals) {
    int i = blockIdx.x * 256 + threadIdx.x;
    float o3[4], o4[4], o5[4];
    deriv_point(g4, g, i, o3, o4, o5);
    float m3, i3, m4, i4, m5, i5;
    mean_inv(finals, 3, m3, i3);
    mean_inv(finals, 4, m4, i4);
    mean_inv(finals, 5, m5, i5);
    c3[i]  = make_float4((o3[0]-m3)*i3, (o3[1]-m3)*i3, (o3[2]-m3)*i3, (o3[3]-m3)*i3);
    c4o[i] = make_float4((o4[0]-m4)*i4, (o4[1]-m4)*i4, (o4[2]-m4)*i4, (o4[3]-m4)*i4);
    c5[i]  = make_float4((o5[0]-m5)*i5, (o5[1]-m5)*i5, (o5[2]-m5)*i5, (o5[3]-m5)*i5);
}

// ---- normalize ch0 (from raw), ch1, ch2 (in place) --------------------------
__global__ __launch_bounds__(256) void norm_abc(const float4* __restrict__ raw,
        float4* __restrict__ out, const double* __restrict__ finals) {
    int i = blockIdx.x * 256 + threadIdx.x;        // < 3*V4
    int c = i / V4;
    int ii = i - c * V4;
    float m, inv;
    mean_inv(finals, c, m, inv);
    float4 v = (c == 0) ? raw[ii] : out[(size_t)c * V4 + ii];
    v.x = (v.x - m) * inv;
    v.y = (v.y - m) * inv;
    v.z = (v.z - m) * inv;
    v.w = (v.w - m) * inv;
    out[(size_t)c * V4 + ii] = v;
}

// ---- host: Gaussian weights ------------------------------------------------
static void gauss_w(double sigma, float* w13, int center) {
    int ks = (int)(4.0 * sigma + 1.0);
    if (ks % 2 == 0) ks++;
    double tmp[13], sum = 0.0;
    for (int i = 0; i < ks; ++i) {
        double x = (double)(i - ks / 2);
        tmp[i] = exp(-0.5 * x * x / (sigma * sigma));
        sum += tmp[i];
    }
    for (int i = 0; i < 13; ++i) w13[i] = 0.f;
    int h = ks / 2;
    for (int i = 0; i < ks; ++i) w13[center + (i - h)] = (float)(tmp[i] / sum);
}

extern "C" void kernel_launch(void* const* d_in, const int* in_sizes, int n_in,
                              void* d_out, int out_size, void* d_ws, size_t ws_size,
                              hipStream_t stream) {
    const float* raw = (const float*)d_in[0];
    float* out = (float*)d_out;
    float* o[6];
    for (int c = 0; c < 6; ++c) o[c] = out + (size_t)c * V;
    double* slots  = (double*)d_ws;                 // 12 * 64 doubles
    double* finals = slots + 12 * NSLOT;            // 12 doubles

    hipMemsetAsync(d_ws, 0, (12 * NSLOT + 12) * sizeof(double), stream);

    // weights (each centered at its own KS/2)
    ZW zw;
    gauss_w(1.0, zw.w10, 6); gauss_w(1.5, zw.w15, 6);
    gauss_w(2.0, zw.w20, 6); gauss_w(3.0, zw.w30, 6);
    W2 wyA; gauss_w(1.0, wyA.wA, 2);  gauss_w(1.5, wyA.wB, 3);   // KY 5, 7
    W2 wxA; gauss_w(1.0, wxA.wA, 2);  gauss_w(1.5, wxA.wB, 3);   // KX 5, 7
    W2 wyB; gauss_w(2.0, wyB.wA, 4);  gauss_w(3.0, wyB.wB, 6);   // KY 9, 13
    W2 wxB; gauss_w(2.0, wxB.wA, 4);  gauss_w(3.0, wxB.wB, 6);   // KX 9, 13

    const float4* raw4 = (const float4*)raw;
    dim3 blk(256);
    int g4blocks = V4 / 256;                 // 6912
    int yxblocks = DIM * (DIM / 16);         // 2304

    // intermediate placement:
    //   g10z (fp32)  -> o5
    //   g15z (fp16)  -> o3 lower half
    //   g20z (fp16)  -> o3 upper half
    //   g30z (fp16)  -> o4 lower half
    float4* g10z = (float4*)o[5];
    uint2*  g15z = (uint2*)o[3];
    uint2*  g20z = (uint2*)o[3] + V4;
    uint2*  g30z = (uint2*)o[4];

    // z-pass (all sigmas) + ch0 stats
    zpass4<<<g4blocks, blk, 0, stream>>>(raw4, g10z, g15z, g20z, g30z, zw, slots);
    // fused y+x, sigma 1.0/1.5: -> G10 (o0), ch1 (o1) + ch1 stats
    yx2<5, 7, 5, 7, true><<<yxblocks, blk, 0, stream>>>(
        (const float4*)g10z, (const uint2*)g15z, (float4*)o[0], (float4*)o[1],
        wyA, wxA, slots + 2 * NSLOT, slots + 3 * NSLOT);
    // fused y+x, sigma 2.0/3.0: -> ch2 (o2) + ch2 stats
    yx2<9, 13, 9, 13, false><<<yxblocks, blk, 0, stream>>>(
        (const uint2*)g20z, (const uint2*)g30z, (float4*)nullptr, (float4*)o[2],
        wyB, wxB, slots + 4 * NSLOT, slots + 5 * NSLOT);
    // ch3/4/5 statistics from G10 (o0), no writes
    deriv_stats<<<g4blocks, blk, 0, stream>>>((const float4*)o[0], o[0], slots);
    // fold slots -> finals
    finalize_sums<<<1, 256, 0, stream>>>(slots, finals);
    // recompute derivatives of G10 -> write normalized ch3(o3), ch4(o4), ch5(o5)
    norm_deriv<<<g4blocks, blk, 0, stream>>>((const float4*)o[0], o[0],
        (float4*)o[3], (float4*)o[4], (float4*)o[5], finals);
    // normalize ch0 (from raw) -> o0, ch1 -> o1, ch2 -> o2
    norm_abc<<<(3 * V4) / 256, blk, 0, stream>>>(raw4, (float4*)out, finals);
}

// Round 6
// 220.917 us; speedup vs baseline: 4.0702x; 1.1173x over previous
//
#include <hip/hip_runtime.h>
#include <hip/hip_fp16.h>
#include <cmath>

#define DIM 192
#define V (DIM * DIM * DIM)          // 7,077,888
#define V4 (V / 4)                   // 1,769,472 float4s
#define ROW4 (DIM / 4)               // 48 float4 per row
#define SLAB4 (ROW4 * DIM)           // 9216 float4 per z-slice
#define NSLOT 64                     // hashed atomic slots per statistic
#define ZB 4                         // z-outputs per thread in zpass
#define TY 16                        // y-rows per yx tile
#define YXB (DIM * (DIM / TY))       // 2304 blocks per sigma-pair

struct ZW { float w10[13], w15[13], w20[13], w30[13]; };
struct W2 { float wA[13], wB[13]; };

__device__ inline void fma4(float4& a, float w, const float4& v) {
    a.x += w * v.x; a.y += w * v.y; a.z += w * v.z; a.w += w * v.w;
}

// ---- fp16 pack/unpack (4 values in a uint2) --------------------------------
__device__ inline uint2 pack_h4(float4 v) {
    __half2 lo = __floats2half2_rn(v.x, v.y);
    __half2 hi = __floats2half2_rn(v.z, v.w);
    uint2 r;
    r.x = *(unsigned int*)&lo;
    r.y = *(unsigned int*)&hi;
    return r;
}
__device__ inline float4 unpack_h4(uint2 p) {
    __half2 lo = *(__half2*)&p.x;
    __half2 hi = *(__half2*)&p.y;
    float2 a = __half22float2(lo), b = __half22float2(hi);
    return make_float4(a.x, a.y, b.x, b.y);
}
__device__ inline float4 ld4(const float4* p, int i) { return p[i]; }
__device__ inline float4 ld4(const uint2*  p, int i) { return unpack_h4(p[i]); }

// block-wide (256 thr) reduce of (s, s2) -> hashed-slot atomicAdd
__device__ inline void block_reduce_slot2(float s, float s2,
                                          double* slots0, double* slots1) {
    __shared__ float ws[4], ws2[4];
    __syncthreads();                       // protect reuse across calls
    for (int m = 1; m < 64; m <<= 1) {
        s  += __shfl_xor(s,  m, 64);
        s2 += __shfl_xor(s2, m, 64);
    }
    int wid = threadIdx.x >> 6, lane = threadIdx.x & 63;
    if (lane == 0) { ws[wid] = s; ws2[wid] = s2; }
    __syncthreads();
    if (threadIdx.x == 0) {
        int slot = blockIdx.x & (NSLOT - 1);
        atomicAdd(&slots0[slot], (double)(ws[0] + ws[1] + ws[2] + ws[3]));
        atomicAdd(&slots1[slot], (double)(ws2[0] + ws2[1] + ws2[2] + ws2[3]));
    }
}

// ---- fused z-pass, 4 sigmas, ZB z-outputs per thread + ch0 stats -----------
__global__ __launch_bounds__(256) void zpass4(const float4* __restrict__ raw,
        float4* __restrict__ g10z, uint2* __restrict__ g15z,
        uint2* __restrict__ g20z, uint2* __restrict__ g30z,
        ZW zw, double* __restrict__ slots) {
    int tid = blockIdx.x * 256 + threadIdx.x;      // [0, V4/ZB)
    int x4 = tid % ROW4;
    int y  = (tid / ROW4) % DIM;
    int zg = tid / (ROW4 * DIM);
    int z0 = zg * ZB;
    int base = y * ROW4 + x4;
    float4 a10[ZB], a15[ZB], a20[ZB], a30[ZB];
#pragma unroll
    for (int k = 0; k < ZB; ++k) {
        a10[k] = make_float4(0,0,0,0); a15[k] = make_float4(0,0,0,0);
        a20[k] = make_float4(0,0,0,0); a30[k] = make_float4(0,0,0,0);
    }
    float s = 0.f, s2 = 0.f;
#pragma unroll
    for (int j = 0; j < ZB + 12; ++j) {            // 16 taps cover ZB windows
        int zz = z0 + j - 6;
        if (zz >= 0 && zz < DIM) {
            float4 v = raw[zz * SLAB4 + base];
#pragma unroll
            for (int k = 0; k < ZB; ++k) {
                int w = j - k;                      // compile-time per (j,k)
                if (w >= 0 && w <= 12) {
                    fma4(a10[k], zw.w10[w], v);
                    fma4(a15[k], zw.w15[w], v);
                    fma4(a20[k], zw.w20[w], v);
                    fma4(a30[k], zw.w30[w], v);
                }
            }
            if (j >= 6 && j < 6 + ZB) {            // v is a center value
                s  += v.x + v.y + v.z + v.w;
                s2 += v.x*v.x + v.y*v.y + v.z*v.z + v.w*v.w;
            }
        }
    }
#pragma unroll
    for (int k = 0; k < ZB; ++k) {
        int idx = (z0 + k) * SLAB4 + base;
        g10z[idx] = a10[k];
        g15z[idx] = pack_h4(a15[k]);
        g20z[idx] = pack_h4(a20[k]);
        g30z[idx] = pack_h4(a30[k]);
    }
    block_reduce_slot2(s, s2, slots + 0 * NSLOT, slots + 1 * NSLOT);
}

// ---- y+x tile body for one sigma pair --------------------------------------
template <int KYA, int KYB, int KXA, int KXB, bool WRITE_G, bool OUT_H,
          typename TA, typename TB>
__device__ void yx_tile(int tile, const TA* __restrict__ inA,
        const TB* __restrict__ inB, float4* __restrict__ outG,
        float4* __restrict__ outCf, uint2* __restrict__ outCh,
        float* yA, float* yB,
        const W2& wy, const W2& wx, double* s0, double* s1) {
    constexpr int NF4 = TY * ROW4;            // 768 float4 per tile
    int z  = tile / (DIM / TY);
    int y0 = (tile % (DIM / TY)) * TY;
    const int slab = z * SLAB4;
    // y-convolution into LDS
    for (int e = threadIdx.x; e < NF4; e += 256) {
        int r  = e / ROW4;
        int x4 = e % ROW4;
        int y  = y0 + r;
        float4 a = {0,0,0,0}, b = {0,0,0,0};
#pragma unroll
        for (int t = 0; t < KYA; ++t) {
            int yy = y + t - KYA / 2;
            if (yy >= 0 && yy < DIM) fma4(a, wy.wA[t], ld4(inA, slab + yy * ROW4 + x4));
        }
#pragma unroll
        for (int t = 0; t < KYB; ++t) {
            int yy = y + t - KYB / 2;
            if (yy >= 0 && yy < DIM) fma4(b, wy.wB[t], ld4(inB, slab + yy * ROW4 + x4));
        }
        int o = r * DIM + x4 * 4;
        yA[o] = a.x; yA[o + 1] = a.y; yA[o + 2] = a.z; yA[o + 3] = a.w;
        yB[o] = b.x; yB[o + 1] = b.y; yB[o + 2] = b.z; yB[o + 3] = b.w;
    }
    __syncthreads();
    float s = 0.f, s2 = 0.f;
    for (int e = threadIdx.x; e < NF4; e += 256) {
        int r = e / ROW4, x4 = e % ROW4;
        int rb = r * DIM;
        float g[4], c[4];
#pragma unroll
        for (int j = 0; j < 4; ++j) {
            int x = x4 * 4 + j;
            float ca = 0.f, cb = 0.f;
#pragma unroll
            for (int t = 0; t < KXA; ++t) {
                int xx = x + t - KXA / 2;
                if (xx >= 0 && xx < DIM) ca += wx.wA[t] * yA[rb + xx];
            }
#pragma unroll
            for (int t = 0; t < KXB; ++t) {
                int xx = x + t - KXB / 2;
                if (xx >= 0 && xx < DIM) cb += wx.wB[t] * yB[rb + xx];
            }
            float ch = ca - cb;
            g[j] = ca; c[j] = ch;
            s += ch; s2 += ch * ch;
        }
        int gi = slab + (y0 + r) * ROW4 + x4;
        if constexpr (WRITE_G) outG[gi] = make_float4(g[0], g[1], g[2], g[3]);
        if constexpr (OUT_H)   outCh[gi] = pack_h4(make_float4(c[0], c[1], c[2], c[3]));
        else                   outCf[gi] = make_float4(c[0], c[1], c[2], c[3]);
    }
    block_reduce_slot2(s, s2, s0, s1);
}

// ---- merged y+x kernel: both sigma pairs in one dispatch -------------------
__global__ __launch_bounds__(256) void yx_both(
        const float4* __restrict__ g10z, const uint2* __restrict__ g15z,
        const uint2* __restrict__ g20z, const uint2* __restrict__ g30z,
        float4* __restrict__ o0, float4* __restrict__ o1, float4* __restrict__ o2,
        uint2* __restrict__ ch1h, uint2* __restrict__ ch2h, int useH,
        W2 wyA, W2 wxA, W2 wyB, W2 wxB, double* __restrict__ slots) {
    __shared__ float yA[TY * DIM], yB[TY * DIM];
    int bid = blockIdx.x;
    if (bid < YXB) {
        if (useH)
            yx_tile<5, 7, 5, 7, true, true>(bid, g10z, g15z, o0, (float4*)nullptr,
                ch1h, yA, yB, wyA, wxA, slots + 2 * NSLOT, slots + 3 * NSLOT);
        else
            yx_tile<5, 7, 5, 7, true, false>(bid, g10z, g15z, o0, o1,
                (uint2*)nullptr, yA, yB, wyA, wxA, slots + 2 * NSLOT, slots + 3 * NSLOT);
    } else {
        bid -= YXB;
        if (useH)
            yx_tile<9, 13, 9, 13, false, true>(bid, g20z, g30z, (float4*)nullptr,
                (float4*)nullptr, ch2h, yA, yB, wyB, wxB,
                slots + 4 * NSLOT, slots + 5 * NSLOT);
        else
            yx_tile<9, 13, 9, 13, false, false>(bid, g20z, g30z, (float4*)nullptr,
                o2, (uint2*)nullptr, yA, yB, wyB, wxB,
                slots + 4 * NSLOT, slots + 5 * NSLOT);
    }
}

// ---- shared derivative math -------------------------------------------------
__device__ inline void deriv_point(const float4* g4, const float* g, int i,
                                   float o3[4], float o4[4], float o5[4]) {
    int x4 = i % ROW4;
    int y  = (i / ROW4) % DIM;
    int z  = i / SLAB4;
    const float4 zero = {0,0,0,0};
    float4 c  = g4[i];
    float4 zm = (z > 0)       ? g4[i - SLAB4] : zero;
    float4 zp = (z < DIM - 1) ? g4[i + SLAB4] : zero;
    float4 ym = (y > 0)       ? g4[i - ROW4]  : zero;
    float4 yp = (y < DIM - 1) ? g4[i + ROW4]  : zero;
    float lf = (x4 > 0)        ? g[4 * i - 1] : 0.f;
    float rt = (x4 < ROW4 - 1) ? g[4 * i + 4] : 0.f;
    float xm[4] = { lf, c.x, c.y, c.z };
    float xp[4] = { c.y, c.z, c.w, rt };
    float cc[4] = { c.x, c.y, c.z, c.w };
    float zmv[4] = { zm.x, zm.y, zm.z, zm.w };
    float zpv[4] = { zp.x, zp.y, zp.z, zp.w };
    float ymv[4] = { ym.x, ym.y, ym.z, ym.w };
    float ypv[4] = { yp.x, yp.y, yp.z, yp.w };
#pragma unroll
    for (int j = 0; j < 4; ++j) {
        float gx = 0.5f * (xp[j] - xm[j]);
        float gy = 0.5f * (ypv[j] - ymv[j]);
        float gz = 0.5f * (zpv[j] - zmv[j]);
        o3[j] = xm[j] + xp[j] + ymv[j] + ypv[j] + zmv[j] + zpv[j] - 6.f * cc[j];
        o4[j] = sqrtf(gx * gx + gy * gy + gz * gz + 1e-8f);
        o5[j] = fminf(fabsf(gy) / (fabsf(gx) + 1e-3f), 20.f);
    }
}

// ---- ch3/4/5 statistics only (no writes) -----------------------------------
__global__ __launch_bounds__(256) void deriv_stats(const float4* __restrict__ g4,
        const float* __restrict__ g, double* __restrict__ slots) {
    int i = blockIdx.x * 256 + threadIdx.x;
    float o3[4], o4[4], o5[4];
    deriv_point(g4, g, i, o3, o4, o5);
    float s3 = 0, q3 = 0, s4 = 0, q4 = 0, s5 = 0, q5 = 0;
#pragma unroll
    for (int j = 0; j < 4; ++j) {
        s3 += o3[j]; q3 += o3[j] * o3[j];
        s4 += o4[j]; q4 += o4[j] * o4[j];
        s5 += o5[j]; q5 += o5[j] * o5[j];
    }
    block_reduce_slot2(s3, q3, slots + 6 * NSLOT,  slots + 7 * NSLOT);
    block_reduce_slot2(s4, q4, slots + 8 * NSLOT,  slots + 9 * NSLOT);
    block_reduce_slot2(s5, q5, slots + 10 * NSLOT, slots + 11 * NSLOT);
}

// ---- fold 64 slots per statistic -> finals[12] (warp-parallel) --------------
__global__ void finalize_sums(const double* __restrict__ slots,
                              double* __restrict__ finals) {
    int w = threadIdx.x >> 6, lane = threadIdx.x & 63;   // 256 thr = 4 waves
    for (int t = w; t < 12; t += 4) {
        double s = slots[t * NSLOT + lane];              // NSLOT == 64
        for (int m = 1; m < 64; m <<= 1) s += __shfl_xor(s, m, 64);
        if (lane == 0) finals[t] = s;
    }
}

__device__ inline void mean_inv(const double* finals, int c, float& m, float& inv) {
    double s = finals[2 * c], s2 = finals[2 * c + 1];
    double mean = s / (double)V;
    double var  = (s2 - s * s / (double)V) / (double)(V - 1);
    m   = (float)mean;
    inv = (float)(1.0 / (sqrt(var) + 1e-8));
}

// ---- recompute derivatives from G10 and write NORMALIZED ch3/4/5 -----------
__global__ __launch_bounds__(256) void norm_deriv(const float4* __restrict__ g4,
        const float* __restrict__ g, float4* __restrict__ c3,
        float4* __restrict__ c4o, float4* __restrict__ c5,
        const double* __restrict__ finals) {
    int i = blockIdx.x * 256 + threadIdx.x;
    float o3[4], o4[4], o5[4];
    deriv_point(g4, g, i, o3, o4, o5);
    float m3, i3, m4, i4, m5, i5;
    mean_inv(finals, 3, m3, i3);
    mean_inv(finals, 4, m4, i4);
    mean_inv(finals, 5, m5, i5);
    c3[i]  = make_float4((o3[0]-m3)*i3, (o3[1]-m3)*i3, (o3[2]-m3)*i3, (o3[3]-m3)*i3);
    c4o[i] = make_float4((o4[0]-m4)*i4, (o4[1]-m4)*i4, (o4[2]-m4)*i4, (o4[3]-m4)*i4);
    c5[i]  = make_float4((o5[0]-m5)*i5, (o5[1]-m5)*i5, (o5[2]-m5)*i5, (o5[3]-m5)*i5);
}

// ---- normalize ch0 (from raw), ch1, ch2 --------------------------------------
__global__ __launch_bounds__(256) void norm_abc(const float4* __restrict__ raw,
        const uint2* __restrict__ ch1h, const uint2* __restrict__ ch2h,
        float4* __restrict__ out, const double* __restrict__ finals, int useH) {
    int i = blockIdx.x * 256 + threadIdx.x;        // < 3*V4
    int c = i / V4;
    int ii = i - c * V4;
    float m, inv;
    mean_inv(finals, c, m, inv);
    float4 v;
    if (c == 0)     v = raw[ii];
    else if (useH)  v = unpack_h4((c == 1 ? ch1h : ch2h)[ii]);
    else            v = out[(size_t)c * V4 + ii];
    v.x = (v.x - m) * inv;
    v.y = (v.y - m) * inv;
    v.z = (v.z - m) * inv;
    v.w = (v.w - m) * inv;
    out[(size_t)c * V4 + ii] = v;
}

// ---- host: Gaussian weights ------------------------------------------------
static void gauss_w(double sigma, float* w13, int center) {
    int ks = (int)(4.0 * sigma + 1.0);
    if (ks % 2 == 0) ks++;
    double tmp[13], sum = 0.0;
    for (int i = 0; i < ks; ++i) {
        double x = (double)(i - ks / 2);
        tmp[i] = exp(-0.5 * x * x / (sigma * sigma));
        sum += tmp[i];
    }
    for (int i = 0; i < 13; ++i) w13[i] = 0.f;
    int h = ks / 2;
    for (int i = 0; i < ks; ++i) w13[center + (i - h)] = (float)(tmp[i] / sum);
}

extern "C" void kernel_launch(void* const* d_in, const int* in_sizes, int n_in,
                              void* d_out, int out_size, void* d_ws, size_t ws_size,
                              hipStream_t stream) {
    const float* raw = (const float*)d_in[0];
    float* out = (float*)d_out;
    float* o[6];
    for (int c = 0; c < 6; ++c) o[c] = out + (size_t)c * V;
    double* slots  = (double*)d_ws;                 // 12 * 64 doubles
    double* finals = slots + 12 * NSLOT;            // 12 doubles

    // optional fp16 staging of pre-norm ch1/ch2 in workspace
    size_t stage_off = 8192;
    size_t stage_need = stage_off + 2 * (size_t)V4 * sizeof(uint2);  // ~28.3 MB
    int useH = (ws_size >= stage_need) ? 1 : 0;
    uint2* ch1h = (uint2*)((char*)d_ws + stage_off);
    uint2* ch2h = ch1h + V4;

    hipMemsetAsync(d_ws, 0, (12 * NSLOT + 12) * sizeof(double), stream);

    // weights (each centered at its own KS/2)
    ZW zw;
    gauss_w(1.0, zw.w10, 6); gauss_w(1.5, zw.w15, 6);
    gauss_w(2.0, zw.w20, 6); gauss_w(3.0, zw.w30, 6);
    W2 wyA; gauss_w(1.0, wyA.wA, 2);  gauss_w(1.5, wyA.wB, 3);   // KY 5, 7
    W2 wxA; gauss_w(1.0, wxA.wA, 2);  gauss_w(1.5, wxA.wB, 3);   // KX 5, 7
    W2 wyB; gauss_w(2.0, wyB.wA, 4);  gauss_w(3.0, wyB.wB, 6);   // KY 9, 13
    W2 wxB; gauss_w(2.0, wxB.wA, 4);  gauss_w(3.0, wxB.wB, 6);   // KX 9, 13

    const float4* raw4 = (const float4*)raw;
    dim3 blk(256);
    int g4blocks = V4 / 256;                 // 6912
    int zblocks  = V4 / (ZB * 256);          // 1728

    // intermediate placement:
    //   g10z (fp32)  -> o5
    //   g15z (fp16)  -> o3 lower half
    //   g20z (fp16)  -> o3 upper half
    //   g30z (fp16)  -> o4 lower half
    float4* g10z = (float4*)o[5];
    uint2*  g15z = (uint2*)o[3];
    uint2*  g20z = (uint2*)o[3] + V4;
    uint2*  g30z = (uint2*)o[4];

    // z-pass (all sigmas, ZB z per thread) + ch0 stats
    zpass4<<<zblocks, blk, 0, stream>>>(raw4, g10z, g15z, g20z, g30z, zw, slots);
    // merged y+x for both sigma pairs:
    //   A: -> G10 (o0), ch1 (o1 fp32 or ch1h fp16) + ch1 stats
    //   B: -> ch2 (o2 fp32 or ch2h fp16) + ch2 stats
    yx_both<<<2 * YXB, blk, 0, stream>>>(g10z, g15z, g20z, g30z,
        (float4*)o[0], (float4*)o[1], (float4*)o[2], ch1h, ch2h, useH,
        wyA, wxA, wyB, wxB, slots);
    // ch3/4/5 statistics from G10 (o0), no writes
    deriv_stats<<<g4blocks, blk, 0, stream>>>((const float4*)o[0], o[0], slots);
    // fold slots -> finals
    finalize_sums<<<1, 256, 0, stream>>>(slots, finals);
    // recompute derivatives of G10 -> write normalized ch3(o3), ch4(o4), ch5(o5)
    norm_deriv<<<g4blocks, blk, 0, stream>>>((const float4*)o[0], o[0],
        (float4*)o[3], (float4*)o[4], (float4*)o[5], finals);
    // normalize ch0 (from raw) -> o0, ch1 -> o1, ch2 -> o2
    norm_abc<<<(3 * V4) / 256, blk, 0, stream>>>(raw4, ch1h, ch2h,
        (float4*)out, finals, useH);
}

// Round 7
// 202.491 us; speedup vs baseline: 4.4406x; 1.0910x over previous
//
#include <hip/hip_runtime.h>
#include <hip/hip_fp16.h>
#include <cmath>

#define DIM 192
#define V (DIM * DIM * DIM)          // 7,077,888
#define V4 (V / 4)                   // 1,769,472 float4s
#define ROW4 (DIM / 4)               // 48 float4 per row
#define SLAB4 (ROW4 * DIM)           // 9216 float4 per z-slice
#define NSLOT 64                     // hashed atomic slots per statistic
#define ZB 4                         // z-outputs per thread in zpass
#define TY 16                        // y-rows per yx tile
#define YXB (DIM * (DIM / TY))       // 2304 blocks per sigma-pair

struct ZW { float w10[13], w15[13], w20[13], w30[13]; };
struct W2 { float wA[13], wB[13]; };

__device__ inline void fma4(float4& a, float w, const float4& v) {
    a.x += w * v.x; a.y += w * v.y; a.z += w * v.z; a.w += w * v.w;
}

// ---- fp16 pack/unpack (4 values in a uint2) --------------------------------
__device__ inline uint2 pack_h4(float4 v) {
    __half2 lo = __floats2half2_rn(v.x, v.y);
    __half2 hi = __floats2half2_rn(v.z, v.w);
    uint2 r;
    r.x = *(unsigned int*)&lo;
    r.y = *(unsigned int*)&hi;
    return r;
}
__device__ inline float4 unpack_h4(uint2 p) {
    __half2 lo = *(__half2*)&p.x;
    __half2 hi = *(__half2*)&p.y;
    float2 a = __half22float2(lo), b = __half22float2(hi);
    return make_float4(a.x, a.y, b.x, b.y);
}
__device__ inline float4 ld4(const float4* p, int i) { return p[i]; }
__device__ inline float4 ld4(const uint2*  p, int i) { return unpack_h4(p[i]); }

// block-wide (256 thr) reduce of (s, s2) -> hashed-slot atomicAdd
__device__ inline void block_reduce_slot2(float s, float s2,
                                          double* slots0, double* slots1) {
    __shared__ float ws[4], ws2[4];
    __syncthreads();                       // protect reuse across calls
    for (int m = 1; m < 64; m <<= 1) {
        s  += __shfl_xor(s,  m, 64);
        s2 += __shfl_xor(s2, m, 64);
    }
    int wid = threadIdx.x >> 6, lane = threadIdx.x & 63;
    if (lane == 0) { ws[wid] = s; ws2[wid] = s2; }
    __syncthreads();
    if (threadIdx.x == 0) {
        int slot = blockIdx.x & (NSLOT - 1);
        atomicAdd(&slots0[slot], (double)(ws[0] + ws[1] + ws[2] + ws[3]));
        atomicAdd(&slots1[slot], (double)(ws2[0] + ws2[1] + ws2[2] + ws2[3]));
    }
}

// ---- fused z-pass, 4 sigmas, ZB z-outputs per thread + ch0 stats -----------
__global__ __launch_bounds__(256) void zpass4(const float4* __restrict__ raw,
        float4* __restrict__ g10z, uint2* __restrict__ g15z,
        uint2* __restrict__ g20z, uint2* __restrict__ g30z,
        ZW zw, double* __restrict__ slots) {
    int tid = blockIdx.x * 256 + threadIdx.x;      // [0, V4/ZB)
    int x4 = tid % ROW4;
    int y  = (tid / ROW4) % DIM;
    int zg = tid / (ROW4 * DIM);
    int z0 = zg * ZB;
    int base = y * ROW4 + x4;
    float4 a10[ZB], a15[ZB], a20[ZB], a30[ZB];
#pragma unroll
    for (int k = 0; k < ZB; ++k) {
        a10[k] = make_float4(0,0,0,0); a15[k] = make_float4(0,0,0,0);
        a20[k] = make_float4(0,0,0,0); a30[k] = make_float4(0,0,0,0);
    }
    float s = 0.f, s2 = 0.f;
#pragma unroll
    for (int j = 0; j < ZB + 12; ++j) {            // 16 taps cover ZB windows
        int zz = z0 + j - 6;
        if (zz >= 0 && zz < DIM) {
            float4 v = raw[zz * SLAB4 + base];
#pragma unroll
            for (int k = 0; k < ZB; ++k) {
                int w = j - k;                      // compile-time per (j,k)
                if (w >= 0 && w <= 12) {
                    fma4(a10[k], zw.w10[w], v);
                    fma4(a15[k], zw.w15[w], v);
                    fma4(a20[k], zw.w20[w], v);
                    fma4(a30[k], zw.w30[w], v);
                }
            }
            if (j >= 6 && j < 6 + ZB) {            // v is a center value
                s  += v.x + v.y + v.z + v.w;
                s2 += v.x*v.x + v.y*v.y + v.z*v.z + v.w*v.w;
            }
        }
    }
#pragma unroll
    for (int k = 0; k < ZB; ++k) {
        int idx = (z0 + k) * SLAB4 + base;
        g10z[idx] = a10[k];
        g15z[idx] = pack_h4(a15[k]);
        g20z[idx] = pack_h4(a20[k]);
        g30z[idx] = pack_h4(a30[k]);
    }
    block_reduce_slot2(s, s2, slots + 0 * NSLOT, slots + 1 * NSLOT);
}

// ---- y+x tile body for one sigma pair (conflict-free float4 LDS) -----------
template <int KYA, int KYB, int KXA, int KXB, bool WRITE_G, bool OUT_H,
          typename TA, typename TB>
__device__ void yx_tile(int tile, const TA* __restrict__ inA,
        const TB* __restrict__ inB, float4* __restrict__ outG,
        float4* __restrict__ outCf, uint2* __restrict__ outCh,
        float4* yA4, float4* yB4,
        const W2& wy, const W2& wx, double* s0, double* s1) {
    constexpr int NF4 = TY * ROW4;            // 768 float4 per tile
    constexpr int HXA = KXA / 2, HXB = KXB / 2;
    constexpr int WQA = (HXA + 3) / 4;        // 1 for K5..K9
    constexpr int WQB = (HXB + 3) / 4;        // 1 for K7/K9, 2 for K13
    int z  = tile / (DIM / TY);
    int y0 = (tile % (DIM / TY)) * TY;
    const int slab = z * SLAB4;
    // y-convolution into LDS (float4 writes, consecutive-lane addresses)
    for (int e = threadIdx.x; e < NF4; e += 256) {
        int r  = e / ROW4;
        int x4 = e % ROW4;
        int y  = y0 + r;
        float4 a = {0,0,0,0}, b = {0,0,0,0};
#pragma unroll
        for (int t = 0; t < KYA; ++t) {
            int yy = y + t - KYA / 2;
            if (yy >= 0 && yy < DIM) fma4(a, wy.wA[t], ld4(inA, slab + yy * ROW4 + x4));
        }
#pragma unroll
        for (int t = 0; t < KYB; ++t) {
            int yy = y + t - KYB / 2;
            if (yy >= 0 && yy < DIM) fma4(b, wy.wB[t], ld4(inB, slab + yy * ROW4 + x4));
        }
        yA4[e] = a;                            // e == r*ROW4 + x4
        yB4[e] = b;
    }
    __syncthreads();
    float s = 0.f, s2 = 0.f;
    for (int e = threadIdx.x; e < NF4; e += 256) {
        int r = e / ROW4, x4 = e % ROW4;
        const float4* rowA = yA4 + r * ROW4;
        const float4* rowB = yB4 + r * ROW4;
        // register windows, loaded via ds_read_b128 (conflict-free)
        float wa[4 * (2 * WQA + 1)], wb[4 * (2 * WQB + 1)];
#pragma unroll
        for (int q = -WQA; q <= WQA; ++q) {
            float4 v = ((unsigned)(x4 + q) < (unsigned)ROW4) ? rowA[x4 + q]
                                                             : make_float4(0,0,0,0);
            int b0 = 4 * (q + WQA);
            wa[b0] = v.x; wa[b0 + 1] = v.y; wa[b0 + 2] = v.z; wa[b0 + 3] = v.w;
        }
#pragma unroll
        for (int q = -WQB; q <= WQB; ++q) {
            float4 v = ((unsigned)(x4 + q) < (unsigned)ROW4) ? rowB[x4 + q]
                                                             : make_float4(0,0,0,0);
            int b0 = 4 * (q + WQB);
            wb[b0] = v.x; wb[b0 + 1] = v.y; wb[b0 + 2] = v.z; wb[b0 + 3] = v.w;
        }
        float g[4], cv[4];
#pragma unroll
        for (int j = 0; j < 4; ++j) {
            float ca = 0.f, cb = 0.f;
#pragma unroll
            for (int t = 0; t < KXA; ++t) ca += wx.wA[t] * wa[4 * WQA + j + t - HXA];
#pragma unroll
            for (int t = 0; t < KXB; ++t) cb += wx.wB[t] * wb[4 * WQB + j + t - HXB];
            g[j] = ca;
            cv[j] = ca - cb;
            s += cv[j]; s2 += cv[j] * cv[j];
        }
        int gi = slab + (y0 + r) * ROW4 + x4;
        if constexpr (WRITE_G) outG[gi] = make_float4(g[0], g[1], g[2], g[3]);
        if constexpr (OUT_H)   outCh[gi] = pack_h4(make_float4(cv[0], cv[1], cv[2], cv[3]));
        else                   outCf[gi] = make_float4(cv[0], cv[1], cv[2], cv[3]);
    }
    block_reduce_slot2(s, s2, s0, s1);
}

// ---- merged y+x kernel: both sigma pairs in one dispatch -------------------
__global__ __launch_bounds__(256) void yx_both(
        const float4* __restrict__ g10z, const uint2* __restrict__ g15z,
        const uint2* __restrict__ g20z, const uint2* __restrict__ g30z,
        float4* __restrict__ o0, float4* __restrict__ o1, float4* __restrict__ o2,
        uint2* __restrict__ ch1h, uint2* __restrict__ ch2h, int useH,
        W2 wyA, W2 wxA, W2 wyB, W2 wxB, double* __restrict__ slots) {
    __shared__ float4 yA4[TY * ROW4], yB4[TY * ROW4];
    int bid = blockIdx.x;
    if (bid < YXB) {
        if (useH)
            yx_tile<5, 7, 5, 7, true, true>(bid, g10z, g15z, o0, (float4*)nullptr,
                ch1h, yA4, yB4, wyA, wxA, slots + 2 * NSLOT, slots + 3 * NSLOT);
        else
            yx_tile<5, 7, 5, 7, true, false>(bid, g10z, g15z, o0, o1,
                (uint2*)nullptr, yA4, yB4, wyA, wxA, slots + 2 * NSLOT, slots + 3 * NSLOT);
    } else {
        bid -= YXB;
        if (useH)
            yx_tile<9, 13, 9, 13, false, true>(bid, g20z, g30z, (float4*)nullptr,
                (float4*)nullptr, ch2h, yA4, yB4, wyB, wxB,
                slots + 4 * NSLOT, slots + 5 * NSLOT);
        else
            yx_tile<9, 13, 9, 13, false, false>(bid, g20z, g30z, (float4*)nullptr,
                o2, (uint2*)nullptr, yA4, yB4, wyB, wxB,
                slots + 4 * NSLOT, slots + 5 * NSLOT);
    }
}

// ---- shared derivative math -------------------------------------------------
__device__ inline void deriv_point(const float4* g4, const float* g, int i,
                                   float o3[4], float o4[4], float o5[4]) {
    int x4 = i % ROW4;
    int y  = (i / ROW4) % DIM;
    int z  = i / SLAB4;
    const float4 zero = {0,0,0,0};
    float4 c  = g4[i];
    float4 zm = (z > 0)       ? g4[i - SLAB4] : zero;
    float4 zp = (z < DIM - 1) ? g4[i + SLAB4] : zero;
    float4 ym = (y > 0)       ? g4[i - ROW4]  : zero;
    float4 yp = (y < DIM - 1) ? g4[i + ROW4]  : zero;
    float lf = (x4 > 0)        ? g[4 * i - 1] : 0.f;
    float rt = (x4 < ROW4 - 1) ? g[4 * i + 4] : 0.f;
    float xm[4] = { lf, c.x, c.y, c.z };
    float xp[4] = { c.y, c.z, c.w, rt };
    float cc[4] = { c.x, c.y, c.z, c.w };
    float zmv[4] = { zm.x, zm.y, zm.z, zm.w };
    float zpv[4] = { zp.x, zp.y, zp.z, zp.w };
    float ymv[4] = { ym.x, ym.y, ym.z, ym.w };
    float ypv[4] = { yp.x, yp.y, yp.z, yp.w };
#pragma unroll
    for (int j = 0; j < 4; ++j) {
        float gx = 0.5f * (xp[j] - xm[j]);
        float gy = 0.5f * (ypv[j] - ymv[j]);
        float gz = 0.5f * (zpv[j] - zmv[j]);
        o3[j] = xm[j] + xp[j] + ymv[j] + ypv[j] + zmv[j] + zpv[j] - 6.f * cc[j];
        o4[j] = sqrtf(gx * gx + gy * gy + gz * gz + 1e-8f);
        o5[j] = fminf(fabsf(gy) / (fabsf(gx) + 1e-3f), 20.f);
    }
}

// ---- ch3/4/5 statistics only (no writes) -----------------------------------
__global__ __launch_bounds__(256) void deriv_stats(const float4* __restrict__ g4,
        const float* __restrict__ g, double* __restrict__ slots) {
    int i = blockIdx.x * 256 + threadIdx.x;
    float o3[4], o4[4], o5[4];
    deriv_point(g4, g, i, o3, o4, o5);
    float s3 = 0, q3 = 0, s4 = 0, q4 = 0, s5 = 0, q5 = 0;
#pragma unroll
    for (int j = 0; j < 4; ++j) {
        s3 += o3[j]; q3 += o3[j] * o3[j];
        s4 += o4[j]; q4 += o4[j] * o4[j];
        s5 += o5[j]; q5 += o5[j] * o5[j];
    }
    block_reduce_slot2(s3, q3, slots + 6 * NSLOT,  slots + 7 * NSLOT);
    block_reduce_slot2(s4, q4, slots + 8 * NSLOT,  slots + 9 * NSLOT);
    block_reduce_slot2(s5, q5, slots + 10 * NSLOT, slots + 11 * NSLOT);
}

// ---- fold 64 slots per statistic -> finals[12] (warp-parallel) --------------
__global__ void finalize_sums(const double* __restrict__ slots,
                              double* __restrict__ finals) {
    int w = threadIdx.x >> 6, lane = threadIdx.x & 63;   // 256 thr = 4 waves
    for (int t = w; t < 12; t += 4) {
        double s = slots[t * NSLOT + lane];              // NSLOT == 64
        for (int m = 1; m < 64; m <<= 1) s += __shfl_xor(s, m, 64);
        if (lane == 0) finals[t] = s;
    }
}

__device__ inline void mean_inv(const double* finals, int c, float& m, float& inv) {
    double s = finals[2 * c], s2 = finals[2 * c + 1];
    double mean = s / (double)V;
    double var  = (s2 - s * s / (double)V) / (double)(V - 1);
    m   = (float)mean;
    inv = (float)(1.0 / (sqrt(var) + 1e-8));
}

// ---- recompute derivatives from G10 and write NORMALIZED ch3/4/5 -----------
__global__ __launch_bounds__(256) void norm_deriv(const float4* __restrict__ g4,
        const float* __restrict__ g, float4* __restrict__ c3,
        float4* __restrict__ c4o, float4* __restrict__ c5,
        const double* __restrict__ finals) {
    int i = blockIdx.x * 256 + threadIdx.x;
    float o3[4], o4[4], o5[4];
    deriv_point(g4, g, i, o3, o4, o5);
    float m3, i3, m4, i4, m5, i5;
    mean_inv(finals, 3, m3, i3);
    mean_inv(finals, 4, m4, i4);
    mean_inv(finals, 5, m5, i5);
    c3[i]  = make_float4((o3[0]-m3)*i3, (o3[1]-m3)*i3, (o3[2]-m3)*i3, (o3[3]-m3)*i3);
    c4o[i] = make_float4((o4[0]-m4)*i4, (o4[1]-m4)*i4, (o4[2]-m4)*i4, (o4[3]-m4)*i4);
    c5[i]  = make_float4((o5[0]-m5)*i5, (o5[1]-m5)*i5, (o5[2]-m5)*i5, (o5[3]-m5)*i5);
}

// ---- normalize ch0 (from raw), ch1, ch2 --------------------------------------
__global__ __launch_bounds__(256) void norm_abc(const float4* __restrict__ raw,
        const uint2* __restrict__ ch1h, const uint2* __restrict__ ch2h,
        float4* __restrict__ out, const double* __restrict__ finals, int useH) {
    int i = blockIdx.x * 256 + threadIdx.x;        // < 3*V4
    int c = i / V4;
    int ii = i - c * V4;
    float m, inv;
    mean_inv(finals, c, m, inv);
    float4 v;
    if (c == 0)     v = raw[ii];
    else if (useH)  v = unpack_h4((c == 1 ? ch1h : ch2h)[ii]);
    else            v = out[(size_t)c * V4 + ii];
    v.x = (v.x - m) * inv;
    v.y = (v.y - m) * inv;
    v.z = (v.z - m) * inv;
    v.w = (v.w - m) * inv;
    out[(size_t)c * V4 + ii] = v;
}

// ---- host: Gaussian weights ------------------------------------------------
static void gauss_w(double sigma, float* w13, int center) {
    int ks = (int)(4.0 * sigma + 1.0);
    if (ks % 2 == 0) ks++;
    double tmp[13], sum = 0.0;
    for (int i = 0; i < ks; ++i) {
        double x = (double)(i - ks / 2);
        tmp[i] = exp(-0.5 * x * x / (sigma * sigma));
        sum += tmp[i];
    }
    for (int i = 0; i < 13; ++i) w13[i] = 0.f;
    int h = ks / 2;
    for (int i = 0; i < ks; ++i) w13[center + (i - h)] = (float)(tmp[i] / sum);
}

extern "C" void kernel_launch(void* const* d_in, const int* in_sizes, int n_in,
                              void* d_out, int out_size, void* d_ws, size_t ws_size,
                              hipStream_t stream) {
    const float* raw = (const float*)d_in[0];
    float* out = (float*)d_out;
    float* o[6];
    for (int c = 0; c < 6; ++c) o[c] = out + (size_t)c * V;
    double* slots  = (double*)d_ws;                 // 12 * 64 doubles
    double* finals = slots + 12 * NSLOT;            // 12 doubles

    // optional fp16 staging of pre-norm ch1/ch2 in workspace
    size_t stage_off = 8192;
    size_t stage_need = stage_off + 2 * (size_t)V4 * sizeof(uint2);  // ~28.3 MB
    int useH = (ws_size >= stage_need) ? 1 : 0;
    uint2* ch1h = (uint2*)((char*)d_ws + stage_off);
    uint2* ch2h = ch1h + V4;

    hipMemsetAsync(d_ws, 0, (12 * NSLOT + 12) * sizeof(double), stream);

    // weights (each centered at its own KS/2)
    ZW zw;
    gauss_w(1.0, zw.w10, 6); gauss_w(1.5, zw.w15, 6);
    gauss_w(2.0, zw.w20, 6); gauss_w(3.0, zw.w30, 6);
    W2 wyA; gauss_w(1.0, wyA.wA, 2);  gauss_w(1.5, wyA.wB, 3);   // KY 5, 7
    W2 wxA; gauss_w(1.0, wxA.wA, 2);  gauss_w(1.5, wxA.wB, 3);   // KX 5, 7
    W2 wyB; gauss_w(2.0, wyB.wA, 4);  gauss_w(3.0, wyB.wB, 6);   // KY 9, 13
    W2 wxB; gauss_w(2.0, wxB.wA, 4);  gauss_w(3.0, wxB.wB, 6);   // KX 9, 13

    const float4* raw4 = (const float4*)raw;
    dim3 blk(256);
    int g4blocks = V4 / 256;                 // 6912
    int zblocks  = V4 / (ZB * 256);          // 1728

    // intermediate placement:
    //   g10z (fp32)  -> o5
    //   g15z (fp16)  -> o3 lower half
    //   g20z (fp16)  -> o3 upper half
    //   g30z (fp16)  -> o4 lower half
    float4* g10z = (float4*)o[5];
    uint2*  g15z = (uint2*)o[3];
    uint2*  g20z = (uint2*)o[3] + V4;
    uint2*  g30z = (uint2*)o[4];

    // z-pass (all sigmas, ZB z per thread) + ch0 stats
    zpass4<<<zblocks, blk, 0, stream>>>(raw4, g10z, g15z, g20z, g30z, zw, slots);
    // merged y+x for both sigma pairs
    yx_both<<<2 * YXB, blk, 0, stream>>>(g10z, g15z, g20z, g30z,
        (float4*)o[0], (float4*)o[1], (float4*)o[2], ch1h, ch2h, useH,
        wyA, wxA, wyB, wxB, slots);
    // ch3/4/5 statistics from G10 (o0), no writes
    deriv_stats<<<g4blocks, blk, 0, stream>>>((const float4*)o[0], o[0], slots);
    // fold slots -> finals
    finalize_sums<<<1, 256, 0, stream>>>(slots, finals);
    // recompute derivatives of G10 -> write normalized ch3(o3), ch4(o4), ch5(o5)
    norm_deriv<<<g4blocks, blk, 0, stream>>>((const float4*)o[0], o[0],
        (float4*)o[3], (float4*)o[4], (float4*)o[5], finals);
    // normalize ch0 (from raw) -> o0, ch1 -> o1, ch2 -> o2
    norm_abc<<<(3 * V4) / 256, blk, 0, stream>>>(raw4, ch1h, ch2h,
        (float4*)out, finals, useH);
}

// Round 8
// 185.002 us; speedup vs baseline: 4.8604x; 1.0945x over previous
//
#include <hip/hip_runtime.h>
#include <hip/hip_fp16.h>
#include <cmath>

#define DIM 192
#define V (DIM * DIM * DIM)          // 7,077,888
#define V4 (V / 4)                   // 1,769,472 float4s
#define ROW4 (DIM / 4)               // 48 float4 per row
#define SLAB4 (ROW4 * DIM)           // 9216 float4 per z-slice
#define NSLOT 64                     // hashed atomic slots per statistic
#define ZB 4                         // z-outputs per thread in zpass
#define TY 16                        // y-rows per yx tile
#define YXB (DIM * (DIM / TY))       // 2304 blocks per sigma-pair

struct ZW { float w10[13], w15[13], w20[13], w30[13]; };
struct W2 { float wA[13], wB[13]; };

__device__ inline void fma4(float4& a, float w, const float4& v) {
    a.x += w * v.x; a.y += w * v.y; a.z += w * v.z; a.w += w * v.w;
}

// bijective XCD-aware swizzle (requires gridDim.x % 8 == 0)
__device__ inline int xcd_swz() {
    int b = blockIdx.x;
    return (b & 7) * (gridDim.x >> 3) + (b >> 3);
}

// ---- fp16 pack/unpack (4 values in a uint2) --------------------------------
__device__ inline uint2 pack_h4(float4 v) {
    __half2 lo = __floats2half2_rn(v.x, v.y);
    __half2 hi = __floats2half2_rn(v.z, v.w);
    uint2 r;
    r.x = *(unsigned int*)&lo;
    r.y = *(unsigned int*)&hi;
    return r;
}
__device__ inline float4 unpack_h4(uint2 p) {
    __half2 lo = *(__half2*)&p.x;
    __half2 hi = *(__half2*)&p.y;
    float2 a = __half22float2(lo), b = __half22float2(hi);
    return make_float4(a.x, a.y, b.x, b.y);
}
__device__ inline float4 ld4(const float4* p, int i) { return p[i]; }
__device__ inline float4 ld4(const uint2*  p, int i) { return unpack_h4(p[i]); }
__device__ inline void   st4(float4* p, int i, float4 v) { p[i] = v; }
__device__ inline void   st4(uint2*  p, int i, float4 v) { p[i] = pack_h4(v); }

// block-wide (256 thr) reduce of (s, s2) -> hashed-slot atomicAdd
__device__ inline void block_reduce_slot2(float s, float s2,
                                          double* slots0, double* slots1) {
    __shared__ float ws[4], ws2[4];
    __syncthreads();                       // protect reuse across calls
    for (int m = 1; m < 64; m <<= 1) {
        s  += __shfl_xor(s,  m, 64);
        s2 += __shfl_xor(s2, m, 64);
    }
    int wid = threadIdx.x >> 6, lane = threadIdx.x & 63;
    if (lane == 0) { ws[wid] = s; ws2[wid] = s2; }
    __syncthreads();
    if (threadIdx.x == 0) {
        int slot = blockIdx.x & (NSLOT - 1);
        atomicAdd(&slots0[slot], (double)(ws[0] + ws[1] + ws[2] + ws[3]));
        atomicAdd(&slots1[slot], (double)(ws2[0] + ws2[1] + ws2[2] + ws2[3]));
    }
}

// fold NSLOT hashed slots for stats [base, base+n) into LDS fin[0..n)
__device__ inline void fold_slots(const double* __restrict__ slots, int base,
                                  int n, double* fin) {
    int w = threadIdx.x >> 6, lane = threadIdx.x & 63;
    for (int t = base + w; t < base + n; t += 4) {
        double s = slots[t * NSLOT + lane];          // NSLOT == 64
        for (int m = 1; m < 64; m <<= 1) s += __shfl_xor(s, m, 64);
        if (lane == 0) fin[t - base] = s;
    }
    __syncthreads();
}

__device__ inline void mean_inv2(double s, double s2, float& m, float& inv) {
    double mean = s / (double)V;
    double var  = (s2 - s * s / (double)V) / (double)(V - 1);
    m   = (float)mean;
    inv = (float)(1.0 / (sqrt(var) + 1e-8));
}

// ---- fused z-pass, 4 sigmas, ZB z-outputs per thread + ch0 stats -----------
__global__ __launch_bounds__(256) void zpass4(const float4* __restrict__ raw,
        float4* __restrict__ g10z, uint2* __restrict__ g15z,
        uint2* __restrict__ g20z, uint2* __restrict__ g30z,
        ZW zw, double* __restrict__ slots) {
    int tid = xcd_swz() * 256 + threadIdx.x;       // [0, V4/ZB)
    int x4 = tid % ROW4;
    int y  = (tid / ROW4) % DIM;
    int zg = tid / (ROW4 * DIM);
    int z0 = zg * ZB;
    int base = y * ROW4 + x4;
    float4 a10[ZB], a15[ZB], a20[ZB], a30[ZB];
#pragma unroll
    for (int k = 0; k < ZB; ++k) {
        a10[k] = make_float4(0,0,0,0); a15[k] = make_float4(0,0,0,0);
        a20[k] = make_float4(0,0,0,0); a30[k] = make_float4(0,0,0,0);
    }
    float s = 0.f, s2 = 0.f;
#pragma unroll
    for (int j = 0; j < ZB + 12; ++j) {            // 16 taps cover ZB windows
        int zz = z0 + j - 6;
        if (zz >= 0 && zz < DIM) {
            float4 v = raw[zz * SLAB4 + base];
#pragma unroll
            for (int k = 0; k < ZB; ++k) {
                int w = j - k;                      // compile-time per (j,k)
                if (w >= 0 && w <= 12) {
                    fma4(a10[k], zw.w10[w], v);
                    fma4(a15[k], zw.w15[w], v);
                    fma4(a20[k], zw.w20[w], v);
                    fma4(a30[k], zw.w30[w], v);
                }
            }
            if (j >= 6 && j < 6 + ZB) {            // v is a center value
                s  += v.x + v.y + v.z + v.w;
                s2 += v.x*v.x + v.y*v.y + v.z*v.z + v.w*v.w;
            }
        }
    }
#pragma unroll
    for (int k = 0; k < ZB; ++k) {
        int idx = (z0 + k) * SLAB4 + base;
        g10z[idx] = a10[k];
        g15z[idx] = pack_h4(a15[k]);
        g20z[idx] = pack_h4(a20[k]);
        g30z[idx] = pack_h4(a30[k]);
    }
    block_reduce_slot2(s, s2, slots + 0 * NSLOT, slots + 1 * NSLOT);
}

// ---- y+x tile body: stage z-volumes in LDS, y-conv from LDS, x-conv --------
template <int KYA, int KYB, int KXA, int KXB, bool WRITE_G, bool OUT_H,
          typename TA, typename TB>
__device__ void yx_tile(int tile, const TA* __restrict__ inA,
        const TB* __restrict__ inB, float4* __restrict__ outG,
        float4* __restrict__ outCf, uint2* __restrict__ outCh,
        char* stage, float4* yA4, float4* yB4,
        const W2& wy, const W2& wx, double* s0, double* s1) {
    constexpr int NF4 = TY * ROW4;            // 768 float4 per tile
    constexpr int HYA = KYA / 2, HYB = KYB / 2;   // HYB >= HYA always
    constexpr int SR  = TY + 2 * HYB;         // staged rows
    constexpr int HXA = KXA / 2, HXB = KXB / 2;
    constexpr int WQA = (HXA + 3) / 4;
    constexpr int WQB = (HXB + 3) / 4;
    TA* sA = (TA*)stage;                       // SR*ROW4 elems
    TB* sB = (TB*)(stage + sizeof(TA) * SR * ROW4);
    int z  = tile / (DIM / TY);
    int y0 = (tile % (DIM / TY)) * TY;
    const int slab = z * SLAB4;
    // ---- stage input rows [y0-HYB, y0+TY-1+HYB], zero-padded ---------------
    for (int e = threadIdx.x; e < SR * ROW4; e += 256) {
        int r  = e / ROW4;
        int x4 = e % ROW4;
        int yy = y0 - HYB + r;
        bool ok = (yy >= 0 && yy < DIM);
        int gi = slab + yy * ROW4 + x4;
        if (ok) { sA[e] = inA[gi]; sB[e] = inB[gi]; }
        else {
            st4(sA, e, make_float4(0,0,0,0));
            st4(sB, e, make_float4(0,0,0,0));
        }
    }
    __syncthreads();
    // ---- y-convolution from LDS into yA4/yB4 -------------------------------
    for (int e = threadIdx.x; e < NF4; e += 256) {
        int r  = e / ROW4;
        int x4 = e % ROW4;
        float4 a = {0,0,0,0}, b = {0,0,0,0};
#pragma unroll
        for (int t = 0; t < KYA; ++t)
            fma4(a, wy.wA[t], ld4(sA, (r + t + HYB - HYA) * ROW4 + x4));
#pragma unroll
        for (int t = 0; t < KYB; ++t)
            fma4(b, wy.wB[t], ld4(sB, (r + t) * ROW4 + x4));
        yA4[e] = a;
        yB4[e] = b;
    }
    __syncthreads();
    // ---- x-convolution via register windows --------------------------------
    float s = 0.f, s2 = 0.f;
    for (int e = threadIdx.x; e < NF4; e += 256) {
        int r = e / ROW4, x4 = e % ROW4;
        const float4* rowA = yA4 + r * ROW4;
        const float4* rowB = yB4 + r * ROW4;
        float wa[4 * (2 * WQA + 1)], wb[4 * (2 * WQB + 1)];
#pragma unroll
        for (int q = -WQA; q <= WQA; ++q) {
            float4 v = ((unsigned)(x4 + q) < (unsigned)ROW4) ? rowA[x4 + q]
                                                             : make_float4(0,0,0,0);
            int b0 = 4 * (q + WQA);
            wa[b0] = v.x; wa[b0 + 1] = v.y; wa[b0 + 2] = v.z; wa[b0 + 3] = v.w;
        }
#pragma unroll
        for (int q = -WQB; q <= WQB; ++q) {
            float4 v = ((unsigned)(x4 + q) < (unsigned)ROW4) ? rowB[x4 + q]
                                                             : make_float4(0,0,0,0);
            int b0 = 4 * (q + WQB);
            wb[b0] = v.x; wb[b0 + 1] = v.y; wb[b0 + 2] = v.z; wb[b0 + 3] = v.w;
        }
        float g[4], cv[4];
#pragma unroll
        for (int j = 0; j < 4; ++j) {
            float ca = 0.f, cb = 0.f;
#pragma unroll
            for (int t = 0; t < KXA; ++t) ca += wx.wA[t] * wa[4 * WQA + j + t - HXA];
#pragma unroll
            for (int t = 0; t < KXB; ++t) cb += wx.wB[t] * wb[4 * WQB + j + t - HXB];
            g[j] = ca;
            cv[j] = ca - cb;
            s += cv[j]; s2 += cv[j] * cv[j];
        }
        int gi = slab + (y0 + r) * ROW4 + x4;
        if constexpr (WRITE_G) outG[gi] = make_float4(g[0], g[1], g[2], g[3]);
        if constexpr (OUT_H)   outCh[gi] = pack_h4(make_float4(cv[0], cv[1], cv[2], cv[3]));
        else                   outCf[gi] = make_float4(cv[0], cv[1], cv[2], cv[3]);
    }
    block_reduce_slot2(s, s2, s0, s1);
}

// stage buffer: max(pairA: 22*48*(16+8)=25344, pairB: 28*48*(8+8)=21504)
#define STAGE_BYTES 25344

// ---- merged y+x kernel: both sigma pairs in one dispatch -------------------
__global__ __launch_bounds__(256) void yx_both(
        const float4* __restrict__ g10z, const uint2* __restrict__ g15z,
        const uint2* __restrict__ g20z, const uint2* __restrict__ g30z,
        float4* __restrict__ o0, float4* __restrict__ o1, float4* __restrict__ o2,
        uint2* __restrict__ ch1h, uint2* __restrict__ ch2h, int useH,
        W2 wyA, W2 wxA, W2 wyB, W2 wxB, double* __restrict__ slots) {
    __shared__ __align__(16) char stage[STAGE_BYTES];
    __shared__ float4 yA4[TY * ROW4], yB4[TY * ROW4];
    int bid = xcd_swz();
    if (bid < YXB) {
        if (useH)
            yx_tile<5, 7, 5, 7, true, true>(bid, g10z, g15z, o0, (float4*)nullptr,
                ch1h, stage, yA4, yB4, wyA, wxA, slots + 2 * NSLOT, slots + 3 * NSLOT);
        else
            yx_tile<5, 7, 5, 7, true, false>(bid, g10z, g15z, o0, o1,
                (uint2*)nullptr, stage, yA4, yB4, wyA, wxA,
                slots + 2 * NSLOT, slots + 3 * NSLOT);
    } else {
        bid -= YXB;
        if (useH)
            yx_tile<9, 13, 9, 13, false, true>(bid, g20z, g30z, (float4*)nullptr,
                (float4*)nullptr, ch2h, stage, yA4, yB4, wyB, wxB,
                slots + 4 * NSLOT, slots + 5 * NSLOT);
        else
            yx_tile<9, 13, 9, 13, false, false>(bid, g20z, g30z, (float4*)nullptr,
                o2, (uint2*)nullptr, stage, yA4, yB4, wyB, wxB,
                slots + 4 * NSLOT, slots + 5 * NSLOT);
    }
}

// ---- shared derivative math -------------------------------------------------
__device__ inline void deriv_point(const float4* g4, const float* g, int i,
                                   float o3[4], float o4[4], float o5[4]) {
    int x4 = i % ROW4;
    int y  = (i / ROW4) % DIM;
    int z  = i / SLAB4;
    const float4 zero = {0,0,0,0};
    float4 c  = g4[i];
    float4 zm = (z > 0)       ? g4[i - SLAB4] : zero;
    float4 zp = (z < DIM - 1) ? g4[i + SLAB4] : zero;
    float4 ym = (y > 0)       ? g4[i - ROW4]  : zero;
    float4 yp = (y < DIM - 1) ? g4[i + ROW4]  : zero;
    float lf = (x4 > 0)        ? g[4 * i - 1] : 0.f;
    float rt = (x4 < ROW4 - 1) ? g[4 * i + 4] : 0.f;
    float xm[4] = { lf, c.x, c.y, c.z };
    float xp[4] = { c.y, c.z, c.w, rt };
    float cc[4] = { c.x, c.y, c.z, c.w };
    float zmv[4] = { zm.x, zm.y, zm.z, zm.w };
    float zpv[4] = { zp.x, zp.y, zp.z, zp.w };
    float ymv[4] = { ym.x, ym.y, ym.z, ym.w };
    float ypv[4] = { yp.x, yp.y, yp.z, yp.w };
#pragma unroll
    for (int j = 0; j < 4; ++j) {
        float gx = 0.5f * (xp[j] - xm[j]);
        float gy = 0.5f * (ypv[j] - ymv[j]);
        float gz = 0.5f * (zpv[j] - zmv[j]);
        o3[j] = xm[j] + xp[j] + ymv[j] + ypv[j] + zmv[j] + zpv[j] - 6.f * cc[j];
        o4[j] = sqrtf(gx * gx + gy * gy + gz * gz + 1e-8f);
        o5[j] = fminf(fabsf(gy) / (fabsf(gx) + 1e-3f), 20.f);
    }
}

// ---- ch3/4/5 statistics only (no writes) -----------------------------------
__global__ __launch_bounds__(256) void deriv_stats(const float4* __restrict__ g4,
        const float* __restrict__ g, double* __restrict__ slots) {
    int i = xcd_swz() * 256 + threadIdx.x;
    float o3[4], o4[4], o5[4];
    deriv_point(g4, g, i, o3, o4, o5);
    float s3 = 0, q3 = 0, s4 = 0, q4 = 0, s5 = 0, q5 = 0;
#pragma unroll
    for (int j = 0; j < 4; ++j) {
        s3 += o3[j]; q3 += o3[j] * o3[j];
        s4 += o4[j]; q4 += o4[j] * o4[j];
        s5 += o5[j]; q5 += o5[j] * o5[j];
    }
    block_reduce_slot2(s3, q3, slots + 6 * NSLOT,  slots + 7 * NSLOT);
    block_reduce_slot2(s4, q4, slots + 8 * NSLOT,  slots + 9 * NSLOT);
    block_reduce_slot2(s5, q5, slots + 10 * NSLOT, slots + 11 * NSLOT);
}

// ---- recompute derivatives from G10 and write NORMALIZED ch3/4/5 -----------
__global__ __launch_bounds__(256) void norm_deriv(const float4* __restrict__ g4,
        const float* __restrict__ g, float4* __restrict__ c3,
        float4* __restrict__ c4o, float4* __restrict__ c5,
        const double* __restrict__ slots) {
    __shared__ double fin[6];
    fold_slots(slots, 6, 6, fin);
    int i = xcd_swz() * 256 + threadIdx.x;
    float o3[4], o4[4], o5[4];
    deriv_point(g4, g, i, o3, o4, o5);
    float m3, i3, m4, i4, m5, i5;
    mean_inv2(fin[0], fin[1], m3, i3);
    mean_inv2(fin[2], fin[3], m4, i4);
    mean_inv2(fin[4], fin[5], m5, i5);
    c3[i]  = make_float4((o3[0]-m3)*i3, (o3[1]-m3)*i3, (o3[2]-m3)*i3, (o3[3]-m3)*i3);
    c4o[i] = make_float4((o4[0]-m4)*i4, (o4[1]-m4)*i4, (o4[2]-m4)*i4, (o4[3]-m4)*i4);
    c5[i]  = make_float4((o5[0]-m5)*i5, (o5[1]-m5)*i5, (o5[2]-m5)*i5, (o5[3]-m5)*i5);
}

// ---- normalize ch0 (from raw), ch1, ch2 --------------------------------------
__global__ __launch_bounds__(256) void norm_abc(const float4* __restrict__ raw,
        const uint2* __restrict__ ch1h, const uint2* __restrict__ ch2h,
        float4* __restrict__ out, const double* __restrict__ slots, int useH) {
    __shared__ double fin[6];
    fold_slots(slots, 0, 6, fin);
    int i = blockIdx.x * 256 + threadIdx.x;        // < 3*V4
    int c = i / V4;
    int ii = i - c * V4;
    float m, inv;
    mean_inv2(fin[2 * c], fin[2 * c + 1], m, inv);
    float4 v;
    if (c == 0)     v = raw[ii];
    else if (useH)  v = unpack_h4((c == 1 ? ch1h : ch2h)[ii]);
    else            v = out[(size_t)c * V4 + ii];
    v.x = (v.x - m) * inv;
    v.y = (v.y - m) * inv;
    v.z = (v.z - m) * inv;
    v.w = (v.w - m) * inv;
    out[(size_t)c * V4 + ii] = v;
}

// ---- host: Gaussian weights ------------------------------------------------
static void gauss_w(double sigma, float* w13, int center) {
    int ks = (int)(4.0 * sigma + 1.0);
    if (ks % 2 == 0) ks++;
    double tmp[13], sum = 0.0;
    for (int i = 0; i < ks; ++i) {
        double x = (double)(i - ks / 2);
        tmp[i] = exp(-0.5 * x * x / (sigma * sigma));
        sum += tmp[i];
    }
    for (int i = 0; i < 13; ++i) w13[i] = 0.f;
    int h = ks / 2;
    for (int i = 0; i < ks; ++i) w13[center + (i - h)] = (float)(tmp[i] / sum);
}

extern "C" void kernel_launch(void* const* d_in, const int* in_sizes, int n_in,
                              void* d_out, int out_size, void* d_ws, size_t ws_size,
                              hipStream_t stream) {
    const float* raw = (const float*)d_in[0];
    float* out = (float*)d_out;
    float* o[6];
    for (int c = 0; c < 6; ++c) o[c] = out + (size_t)c * V;
    double* slots = (double*)d_ws;                  // 12 * 64 doubles

    // optional fp16 staging of pre-norm ch1/ch2 in workspace
    size_t stage_off = 8192;
    size_t stage_need = stage_off + 2 * (size_t)V4 * sizeof(uint2);  // ~28.3 MB
    int useH = (ws_size >= stage_need) ? 1 : 0;
    uint2* ch1h = (uint2*)((char*)d_ws + stage_off);
    uint2* ch2h = ch1h + V4;

    hipMemsetAsync(d_ws, 0, 12 * NSLOT * sizeof(double), stream);

    // weights (each centered at its own KS/2)
    ZW zw;
    gauss_w(1.0, zw.w10, 6); gauss_w(1.5, zw.w15, 6);
    gauss_w(2.0, zw.w20, 6); gauss_w(3.0, zw.w30, 6);
    W2 wyA; gauss_w(1.0, wyA.wA, 2);  gauss_w(1.5, wyA.wB, 3);   // KY 5, 7
    W2 wxA; gauss_w(1.0, wxA.wA, 2);  gauss_w(1.5, wxA.wB, 3);   // KX 5, 7
    W2 wyB; gauss_w(2.0, wyB.wA, 4);  gauss_w(3.0, wyB.wB, 6);   // KY 9, 13
    W2 wxB; gauss_w(2.0, wxB.wA, 4);  gauss_w(3.0, wxB.wB, 6);   // KX 9, 13

    const float4* raw4 = (const float4*)raw;
    dim3 blk(256);
    int g4blocks = V4 / 256;                 // 6912
    int zblocks  = V4 / (ZB * 256);          // 1728

    // intermediate placement:
    //   g10z (fp32)  -> o5
    //   g15z (fp16)  -> o3 lower half
    //   g20z (fp16)  -> o3 upper half
    //   g30z (fp16)  -> o4 lower half
    float4* g10z = (float4*)o[5];
    uint2*  g15z = (uint2*)o[3];
    uint2*  g20z = (uint2*)o[3] + V4;
    uint2*  g30z = (uint2*)o[4];

    // z-pass (all sigmas, ZB z per thread) + ch0 stats
    zpass4<<<zblocks, blk, 0, stream>>>(raw4, g10z, g15z, g20z, g30z, zw, slots);
    // merged y+x for both sigma pairs (LDS-staged y-conv)
    yx_both<<<2 * YXB, blk, 0, stream>>>(g10z, g15z, g20z, g30z,
        (float4*)o[0], (float4*)o[1], (float4*)o[2], ch1h, ch2h, useH,
        wyA, wxA, wyB, wxB, slots);
    // ch3/4/5 statistics from G10 (o0), no writes
    deriv_stats<<<g4blocks, blk, 0, stream>>>((const float4*)o[0], o[0], slots);
    // recompute derivatives of G10 -> write normalized ch3(o3), ch4(o4), ch5(o5)
    norm_deriv<<<g4blocks, blk, 0, stream>>>((const float4*)o[0], o[0],
        (float4*)o[3], (float4*)o[4], (float4*)o[5], slots);
    // normalize ch0 (from raw) -> o0, ch1 -> o1, ch2 -> o2
    norm_abc<<<(3 * V4) / 256, blk, 0, stream>>>(raw4, ch1h, ch2h,
        (float4*)out, slots, useH);
}